// Round 12
// baseline (3516.199 us; speedup 1.0000x reference)
//
#include <hip/hip_runtime.h>

// Problem constants
#define B_  4096
#define T_  64
#define D_  256
#define E_  128
#define H_  256

typedef __attribute__((ext_vector_type(8))) short short8;
typedef __attribute__((ext_vector_type(4))) float f32x4;
typedef __attribute__((ext_vector_type(16))) float f32x16;
typedef __attribute__((ext_vector_type(2))) unsigned int u32x2;

__device__ inline unsigned short f2bf(float f){
  unsigned u = __float_as_uint(f);
  u += 0x7FFFu + ((u >> 16) & 1u);   // RNE
  return (unsigned short)(u >> 16);
}
__device__ inline float bf2f(unsigned short v){
  return __uint_as_float(((unsigned)v) << 16);
}
__device__ inline float sigm_(float x){ return __fdividef(1.f, 1.f + __expf(-x)); }
__device__ inline float tanh_(float x){
  float e = __expf(2.f * fminf(fmaxf(x, -15.f), 15.f));
  return __fdividef(e - 1.f, e + 1.f);
}
__device__ inline short8 ntload8(const unsigned short* p){
  return __builtin_nontemporal_load((const short8*)p);
}
__device__ inline f32x4 ntload4f(const float* p){
  return __builtin_nontemporal_load((const f32x4*)p);
}

// ---------------------------------------------------------------------------
// init: pack weights as 32x32x16 MFMA A-fragments per slice (R7 layout,
// HW-verified): Wf[((s*4+nf)*24 + ks)*512 + l*8 + e]
//   r = l&31: q = r&3, hl = r>>2; h = s*32 + nf*8 + hl
//   k = ks*16 + (l>>5)*8 + e; g = q*256 + h
//   val = k<128 ? W_ih[g][k] : W_hh[g][k-128]
// biasc[h*4+q]; zero hgF buf0 (2 MB); zero cnt (32 x 128B lines).
// grid 1536 x 256.
// ---------------------------------------------------------------------------
__global__ __launch_bounds__(256) void init_kernel(
    const float* __restrict__ W_ih, const float* __restrict__ b_ih,
    const float* __restrict__ W_hh, const float* __restrict__ b_hh,
    unsigned short* __restrict__ Wf, float* __restrict__ biasc,
    unsigned short* __restrict__ hgF, int* __restrict__ cnt){
  const int idx  = blockIdx.x*256 + threadIdx.x;
  const int e    = idx & 7;
  const int l    = (idx >> 3) & 63;
  const int fk   = idx >> 9;          // (s*4+nf)*24 + ks
  const int ks   = fk % 24;
  const int nfs  = fk / 24;
  const int nf   = nfs & 3;
  const int s    = nfs >> 2;
  const int r    = l & 31;
  const int q    = r & 3;
  const int hl   = r >> 2;
  const int h    = s*32 + nf*8 + hl;
  const int k    = ks*16 + (l >> 5)*8 + e;
  const int g    = q*H_ + h;
  float v = (k < E_) ? W_ih[g*E_ + k] : W_hh[g*H_ + (k - E_)];
  Wf[idx] = f2bf(v);
  if (idx < 4*H_){
    int hh = idx >> 2, qq = idx & 3, gg = qq*H_ + hh;
    biasc[idx] = b_ih[gg] + b_hh[gg];
  }
  if (idx < 262144) ((unsigned long long*)hgF)[idx] = 0ull;   // buf0 = 2 MB zeros
  if (idx < 1024) cnt[idx] = 0;
}

// ---------------------------------------------------------------------------
// enc: encF = bf16(tanh(x @ W_enc^T + b_enc)) stored in B-fragment order:
// byte addr = ((t*32 + g)*32 + rg*8 + kw)*1024 + (l31 + 32*l5)*16 + ee*2
//   where b = g*128 + rg*32 + l31 ; ecol = kw*16 + l5*8 + ee.
// ---------------------------------------------------------------------------
__global__ __launch_bounds__(256) void enc_kernel(
    const float* __restrict__ x, const float* __restrict__ W_enc,
    const float* __restrict__ b_enc, unsigned short* __restrict__ encF){
  __shared__ unsigned short As[128*64];
  __shared__ unsigned short Bs[128*64];
  __shared__ float bes[128];
  const int tid = threadIdx.x;
  const int lane = tid & 63, w = tid >> 6;
  const int l15 = lane & 15, lq = lane >> 4;
  const int m0 = blockIdx.x * 128;
  if (tid < 128) bes[tid] = b_enc[tid];

  f32x4 acc[16];
  #pragma unroll
  for (int i=0;i<16;i++) acc[i] = (f32x4)0.f;

  for (int kc = 0; kc < 4; ++kc){
    const int kb = kc*64;
    __syncthreads();
    #pragma unroll
    for (int i=0;i<4;i++){
      int u = i*256 + tid; int r = u>>3, sx = u&7;
      const float* sp = x + (size_t)(m0+r)*D_ + kb + sx*8;
      f32x4 v0 = ntload4f(sp);
      f32x4 v1 = ntload4f(sp+4);
      short8 pk;
      pk[0]=(short)f2bf(v0[0]); pk[1]=(short)f2bf(v0[1]); pk[2]=(short)f2bf(v0[2]); pk[3]=(short)f2bf(v0[3]);
      pk[4]=(short)f2bf(v1[0]); pk[5]=(short)f2bf(v1[1]); pk[6]=(short)f2bf(v1[2]); pk[7]=(short)f2bf(v1[3]);
      int off = (r*128 + sx*16) ^ ((r&7)<<4);
      *(short8*)((char*)As + off) = pk;
    }
    #pragma unroll
    for (int i=0;i<4;i++){
      int u = i*256 + tid; int r = u>>3, sx = u&7;
      const float* sp = W_enc + (size_t)r*D_ + kb + sx*8;
      f32x4 v0 = *(const f32x4*)sp;
      f32x4 v1 = *(const f32x4*)(sp+4);
      short8 pk;
      pk[0]=(short)f2bf(v0[0]); pk[1]=(short)f2bf(v0[1]); pk[2]=(short)f2bf(v0[2]); pk[3]=(short)f2bf(v0[3]);
      pk[4]=(short)f2bf(v1[0]); pk[5]=(short)f2bf(v1[1]); pk[6]=(short)f2bf(v1[2]); pk[7]=(short)f2bf(v1[3]);
      int off = (r*128 + sx*16) ^ ((r&7)<<4);
      *(short8*)((char*)Bs + off) = pk;
    }
    __syncthreads();
    #pragma unroll
    for (int kk=0;kk<2;kk++){
      short8 af[2];
      #pragma unroll
      for (int mi=0;mi<2;mi++){
        int r = 32*w + mi*16 + l15;
        int off = (r*128 + kk*64 + lq*16) ^ ((r&7)<<4);
        af[mi] = *(const short8*)((const char*)As + off);
      }
      #pragma unroll
      for (int nf=0;nf<8;nf++){
        int r = nf*16 + l15;
        int off = (r*128 + kk*64 + lq*16) ^ ((r&7)<<4);
        short8 bfr = *(const short8*)((const char*)Bs + off);
        #pragma unroll
        for (int mi=0;mi<2;mi++)
          acc[mi*8+nf] = __builtin_amdgcn_mfma_f32_16x16x32_bf16(af[mi], bfr, acc[mi*8+nf], 0,0,0);
      }
    }
  }
  #pragma unroll
  for (int mi=0;mi<2;mi++){
    #pragma unroll
    for (int nf=0;nf<8;nf++){
      int col = nf*16 + l15;
      float be = bes[col];
      #pragma unroll
      for (int j=0;j<4;j++){
        int bt = m0 + 32*w + mi*16 + lq*4 + j;
        int b = bt >> 6, tt = bt & 63;
        int gg = b >> 7, rg = (b >> 5) & 3, l31b = b & 31;
        int kw = col >> 4, l5b = (col >> 3) & 1, ee = col & 7;
        size_t byteoff = ((((size_t)tt*32 + gg)*32 + rg*8 + kw) << 10)
                       + (l31b + 32*l5b)*16 + ee*2;
        *(unsigned short*)((char*)encF + byteoff) = f2bf(tanh_(acc[mi*8+nf][j] + be));
      }
    }
  }
}

// ---------------------------------------------------------------------------
// Gate-split LSTM recurrence, LDS-resident weights, fragment-order exchange.
// 256 blocks x 512 threads (1 block/CU). block = (s = bx>>5 gate-slice,
// g = bx&31 batch-group of 128 rows). Group g's 8 blocks {s*32+g} land on one
// XCD (32 = 0 mod 8). Weights: 96 KB slice in LDS, loaded ONCE. Per step:
// wait(cnt[g] >= 8t) -> MFMA (A=weights LDS, B=act frags from encF/hgF,
// coalesced 1KB/wave) -> pointwise (c in regs) -> h to LDS stage -> repack to
// hgF[(t+1)&1] in frag order + full-line ldt/psq/ldim -> post cnt[g]++.
// cnt[g] has a private 128-B line. Guard bails (visible error, no hang).
// ---------------------------------------------------------------------------
__global__ __launch_bounds__(512) void rec_kernel(
    const unsigned short* __restrict__ encF,
    const unsigned short* __restrict__ Wf,
    const float* __restrict__ biasc,
    const float* __restrict__ x,
    unsigned short* __restrict__ hgF,     // [2][32][4][16][512] bf16 frags
    int* __restrict__ cnt,                // 32 x (128B line)
    unsigned short* __restrict__ psq,     // [63][8][4096] bf16
    float* __restrict__ out_hn,
    float* __restrict__ out_ldim,
    float* __restrict__ out_ldt){
  extern __shared__ char smem[];
  char* wlds   = smem;                    // 96 KB weight A-frags
  char* hstage = smem + 98304;            // 128 rows x 80 B (bf16 h), 10240 B
  const int tid = threadIdx.x, lane = tid & 63, w = tid >> 6;
  const int l31 = lane & 31, l5 = lane >> 5;
  const int s  = blockIdx.x >> 5;
  const int g  = blockIdx.x & 31;
  const int b0 = g * 128;
  const int bg = w & 3, np = w >> 2;

  // weights -> LDS (coalesced, once)
  {
    const short8* src = (const short8*)(Wf + (size_t)s*49152);
    short8* dst = (short8*)wlds;
    for (int i = tid; i < 6144; i += 512) dst[i] = src[i];
  }

  // biases for the 2 nf this wave owns
  float biasr[2][16];
  #pragma unroll
  for (int n=0;n<2;n++)
    #pragma unroll
    for (int reg=0;reg<16;reg++){
      int q = reg & 3, hl = 2*(reg>>2) + l5;
      int h = s*32 + (np*2+n)*8 + hl;
      biasr[n][reg] = biasc[h*4 + q];
    }

  const char* abase0 = wlds + (((np*2+0)*24) << 10) + lane*16;  // + ks<<10
  const char* abase1 = wlds + (((np*2+1)*24) << 10) + lane*16;
  const char* ebase  = (const char*)encF + ((size_t)(g*32 + bg*8) << 10) + lane*16;
  const char* hbase  = (const char*)hgF  + ((size_t)((g*4 + bg)*16) << 10) + lane*16;
  // repack: wave w writes frag (rg = w>>1, kwl = w&1), ksub = s*2+kwl
  char* hgFw = (char*)hgF + ((size_t)(((g*4 + (w>>1))*16) + s*2 + (w&1)) << 10) + lane*16;
  const int hsrd = ((w>>1)*32 + l31)*80 + (w&1)*32 + l5*16;    // LDS byte

  float c[8];
  #pragma unroll
  for (int i=0;i<8;i++) c[i] = 0.f;
  f32x4 ldacc[2];
  ldacc[0] = (f32x4)0.f; ldacc[1] = (f32x4)0.f;

  __syncthreads();   // wlds ready

  for (int t=0; t<T_; ++t){
    // ---- wait for group (all 8 slices posted h(t)) ----
    if (tid == 0 && t > 0){
      const int target = 8*t;
      int guard = 0;
      while (__hip_atomic_load(cnt + g*32, __ATOMIC_ACQUIRE,
                               __HIP_MEMORY_SCOPE_AGENT) < target){
        if (++guard > (1<<16)) break;     // bail -> wrong result, not a hang
        __builtin_amdgcn_s_sleep(2);
      }
    }
    __syncthreads();
    __builtin_amdgcn_fence(__ATOMIC_ACQUIRE, "agent");

    // prefetch x stripes for the output pass (hidden under MFMA)
    f32x4 xv[2];
    if (t < T_-1){
      #pragma unroll
      for (int r8=0;r8<2;r8++){
        int row = w*16 + r8*8 + (lane>>3);
        xv[r8] = ntload4f(x + (((size_t)(b0+row)*T_ + t+1)*D_ + s*32 + (lane&7)*4));
      }
    }

    // ---- MFMA: D[32 gates][32 rows] over K=384 ----
    const char* et = ebase + ((size_t)t << 20);
    const char* ht = hbase + ((size_t)(t&1) << 21);
    f32x16 a0 = (f32x16)0.f, a1 = (f32x16)0.f;
    short8 bcur = *(const short8*)et;
    #pragma unroll
    for (int ks=0; ks<24; ++ks){
      short8 bnext = bcur;
      if (ks < 23){
        int kn = ks+1;
        bnext = (kn < 8) ? *(const short8*)(et + ((size_t)kn<<10))
                         : *(const short8*)(ht + ((size_t)(kn-8)<<10));
      }
      short8 A0 = *(const short8*)(abase0 + (ks<<10));
      short8 A1 = *(const short8*)(abase1 + (ks<<10));
      a0 = __builtin_amdgcn_mfma_f32_32x32x16_bf16(A0, bcur, a0, 0,0,0);
      a1 = __builtin_amdgcn_mfma_f32_32x32x16_bf16(A1, bcur, a1, 0,0,0);
      bcur = bnext;
    }

    // ---- pointwise: lane owns batch row bg*32+l31, 8 cells (2 nf x 4 r2) ----
    const int prow = bg*32 + l31;
    #pragma unroll
    for (int n=0;n<2;n++){
      #pragma unroll
      for (int r2=0;r2<4;r2++){
        float g0,g1,g2,g3;
        if (n==0){
          g0=a0[r2*4+0]; g1=a0[r2*4+1]; g2=a0[r2*4+2]; g3=a0[r2*4+3];
        } else {
          g0=a1[r2*4+0]; g1=a1[r2*4+1]; g2=a1[r2*4+2]; g3=a1[r2*4+3];
        }
        float gi = sigm_(g0 + biasr[n][r2*4+0]);
        float gf = sigm_(g1 + biasr[n][r2*4+1]);
        float gg = tanh_(g2 + biasr[n][r2*4+2]);
        float go = sigm_(g3 + biasr[n][r2*4+3]);
        float cn = gf*c[n*4+r2] + gi*gg;
        c[n*4+r2] = cn;
        float hn = go * tanh_(cn);
        int hh = (np*2+n)*8 + 2*r2 + l5;
        *(unsigned short*)(hstage + prow*80 + hh*2) = f2bf(hn);
      }
    }
    __syncthreads();   // hstage complete

    // ---- repack h -> hgF[(t+1)&1] in fragment order (1 frag per wave) ----
    if (t < T_-1){
      short8 hv = *(const short8*)(hstage + hsrd);
      *(short8*)(hgFw + ((size_t)((t+1)&1) << 21)) = hv;
    }

    // ---- outputs: full-line ldt + psq partial + ldim accum (or h_n) ----
    #pragma unroll
    for (int r8=0;r8<2;r8++){
      int row = w*16 + r8*8 + (lane>>3);
      u32x2 hb = *(const u32x2*)(hstage + row*80 + (lane&7)*8);
      f32x4 hf;
      hf[0] = bf2f((unsigned short)(hb[0] & 0xFFFFu));
      hf[1] = bf2f((unsigned short)(hb[0] >> 16));
      hf[2] = bf2f((unsigned short)(hb[1] & 0xFFFFu));
      hf[3] = bf2f((unsigned short)(hb[1] >> 16));
      float* ltp = out_ldt + (((size_t)(b0+row)*T_ + t)*D_ + s*32 + (lane&7)*4);
      if (t < T_-1){
        f32x4 d;
        d[0] = fabsf(hf[0] - xv[r8][0]);
        d[1] = fabsf(hf[1] - xv[r8][1]);
        d[2] = fabsf(hf[2] - xv[r8][2]);
        d[3] = fabsf(hf[3] - xv[r8][3]);
        __builtin_nontemporal_store(d, (f32x4*)ltp);
        ldacc[r8] += d;
        float ss = d[0]*d[0] + d[1]*d[1] + d[2]*d[2] + d[3]*d[3];
        ss += __shfl_xor(ss, 1);
        ss += __shfl_xor(ss, 2);
        ss += __shfl_xor(ss, 4);
        if ((lane & 7) == 0)
          psq[((size_t)t*8 + s)*4096 + b0 + row] = f2bf(ss);
      } else {
        __builtin_nontemporal_store((f32x4)0.f, (f32x4*)ltp);
        __builtin_nontemporal_store(hf,
            (f32x4*)(out_hn + ((size_t)(b0+row)*H_ + s*32 + (lane&7)*4)));
      }
    }

    // ---- post ----
    if (t < T_-1){
      __builtin_amdgcn_fence(__ATOMIC_RELEASE, "agent");
      __syncthreads();
      if (tid == 0)
        __hip_atomic_fetch_add(cnt + g*32, 1, __ATOMIC_RELEASE,
                               __HIP_MEMORY_SCOPE_AGENT);
    }
  }

  // epilogue: loss_dim
  const float inv = 1.f/63.f;
  #pragma unroll
  for (int r8=0;r8<2;r8++){
    int row = w*16 + r8*8 + (lane>>3);
    *(f32x4*)(out_ldim + ((size_t)(b0+row)*H_ + s*32 + (lane&7)*4)) = ldacc[r8]*inv;
  }
}

// ---------------------------------------------------------------------------
// final: loss[b] = (1/63) sum_t sqrt(sum_s psq[t][s][b]). grid 16 x 256.
// ---------------------------------------------------------------------------
__global__ __launch_bounds__(256) void final_kernel(
    const unsigned short* __restrict__ psq, float* __restrict__ out_loss){
  const int w = threadIdx.x >> 6, lane = threadIdx.x & 63;
  const int b = (blockIdx.x*4 + w)*64 + lane;
  float lacc = 0.f;
  for (int t=0;t<T_-1;++t){
    float sum = 0.f;
    #pragma unroll
    for (int s=0;s<8;s++) sum += bf2f(psq[((size_t)t*8 + s)*4096 + b]);
    lacc += sqrtf(sum);
  }
  out_loss[b] = lacc * (1.f/63.f);
}

// ---------------------------------------------------------------------------
extern "C" void kernel_launch(void* const* d_in, const int* in_sizes, int n_in,
                              void* d_out, int out_size, void* d_ws, size_t ws_size,
                              hipStream_t stream){
  const float* x     = (const float*)d_in[0];
  const float* W_enc = (const float*)d_in[1];
  const float* b_enc = (const float*)d_in[2];
  const float* W_ih  = (const float*)d_in[3];
  const float* b_ih  = (const float*)d_in[4];
  const float* W_hh  = (const float*)d_in[5];
  const float* b_hh  = (const float*)d_in[6];

  // ws: encF 64MB | Wf 768KB | biasc 4KB | hgF 4MB | cnt 4KB | psq 4MB
  char* ws = (char*)d_ws;
  unsigned short* encF  = (unsigned short*)(ws);                 // 67,108,864
  unsigned short* Wf    = (unsigned short*)(ws + 67108864);      //    786,432
  float*          biasc = (float*)         (ws + 67895296);      //      4,096
  unsigned short* hgF   = (unsigned short*)(ws + 67899392);      //  4,194,304
  int*            cnt   = (int*)           (ws + 72093696);      //      4,096
  unsigned short* psq   = (unsigned short*)(ws + 72097792);      //  4,128,768
  // total 76,226,560 B

  float* out_hn   = (float*)d_out;
  float* out_loss = out_hn  + (size_t)B_*H_;
  float* out_ldim = out_loss + B_;
  float* out_ldt  = out_ldim + (size_t)B_*H_;

  (void)hipFuncSetAttribute((const void*)rec_kernel,
      hipFuncAttributeMaxDynamicSharedMemorySize, 108544);

  init_kernel<<<1536, 256, 0, stream>>>(W_ih, b_ih, W_hh, b_hh, Wf, biasc, hgF, cnt);
  enc_kernel<<<2048, 256, 0, stream>>>(x, W_enc, b_enc, encF);
  rec_kernel<<<256, 512, 108544, stream>>>(encF, Wf, biasc, x, hgF, cnt, psq,
                                           out_hn, out_ldim, out_ldt);
  final_kernel<<<16, 256, 0, stream>>>(psq, out_loss);
}

// Round 13
// 1458.351 us; speedup vs baseline: 2.4111x; 2.4111x over previous
//
#include <hip/hip_runtime.h>

// Problem constants
#define B_  4096
#define T_  64
#define D_  256
#define E_  128
#define H_  256

typedef __attribute__((ext_vector_type(8))) short short8;
typedef __attribute__((ext_vector_type(4))) float f32x4;
typedef __attribute__((ext_vector_type(16))) float f32x16;
typedef __attribute__((ext_vector_type(2))) unsigned int u32x2;

__device__ inline unsigned short f2bf(float f){
  unsigned u = __float_as_uint(f);
  u += 0x7FFFu + ((u >> 16) & 1u);   // RNE
  return (unsigned short)(u >> 16);
}
__device__ inline float bf2f(unsigned short v){
  return __uint_as_float(((unsigned)v) << 16);
}
__device__ inline float sigm_(float x){ return __fdividef(1.f, 1.f + __expf(-x)); }
__device__ inline float tanh_(float x){
  float e = __expf(2.f * fminf(fmaxf(x, -15.f), 15.f));
  return __fdividef(e - 1.f, e + 1.f);
}
__device__ inline short8 ntload8(const unsigned short* p){
  return __builtin_nontemporal_load((const short8*)p);
}
__device__ inline f32x4 ntload4f(const float* p){
  return __builtin_nontemporal_load((const f32x4*)p);
}

// ---------------------------------------------------------------------------
// init: pack weights as 32x32x16 MFMA A-fragments per slice (R12 layout).
// ---------------------------------------------------------------------------
__global__ __launch_bounds__(256) void init_kernel(
    const float* __restrict__ W_ih, const float* __restrict__ b_ih,
    const float* __restrict__ W_hh, const float* __restrict__ b_hh,
    unsigned short* __restrict__ Wf, float* __restrict__ biasc,
    unsigned short* __restrict__ hgF, int* __restrict__ cnt){
  const int idx  = blockIdx.x*256 + threadIdx.x;
  const int e    = idx & 7;
  const int l    = (idx >> 3) & 63;
  const int fk   = idx >> 9;          // (s*4+nf)*24 + ks
  const int ks   = fk % 24;
  const int nfs  = fk / 24;
  const int nf   = nfs & 3;
  const int s    = nfs >> 2;
  const int r    = l & 31;
  const int q    = r & 3;
  const int hl   = r >> 2;
  const int h    = s*32 + nf*8 + hl;
  const int k    = ks*16 + (l >> 5)*8 + e;
  const int g    = q*H_ + h;
  float v = (k < E_) ? W_ih[g*E_ + k] : W_hh[g*H_ + (k - E_)];
  Wf[idx] = f2bf(v);
  if (idx < 4*H_){
    int hh = idx >> 2, qq = idx & 3, gg = qq*H_ + hh;
    biasc[idx] = b_ih[gg] + b_hh[gg];
  }
  if (idx < 262144) ((unsigned long long*)hgF)[idx] = 0ull;   // buf0 = 2 MB zeros
  if (idx < 1024) cnt[idx] = 0;
}

// ---------------------------------------------------------------------------
// enc: encF = bf16(tanh(x @ W_enc^T + b_enc)) in B-fragment order (R12).
// ---------------------------------------------------------------------------
__global__ __launch_bounds__(256) void enc_kernel(
    const float* __restrict__ x, const float* __restrict__ W_enc,
    const float* __restrict__ b_enc, unsigned short* __restrict__ encF){
  __shared__ unsigned short As[128*64];
  __shared__ unsigned short Bs[128*64];
  __shared__ float bes[128];
  const int tid = threadIdx.x;
  const int lane = tid & 63, w = tid >> 6;
  const int l15 = lane & 15, lq = lane >> 4;
  const int m0 = blockIdx.x * 128;
  if (tid < 128) bes[tid] = b_enc[tid];

  f32x4 acc[16];
  #pragma unroll
  for (int i=0;i<16;i++) acc[i] = (f32x4)0.f;

  for (int kc = 0; kc < 4; ++kc){
    const int kb = kc*64;
    __syncthreads();
    #pragma unroll
    for (int i=0;i<4;i++){
      int u = i*256 + tid; int r = u>>3, sx = u&7;
      const float* sp = x + (size_t)(m0+r)*D_ + kb + sx*8;
      f32x4 v0 = ntload4f(sp);
      f32x4 v1 = ntload4f(sp+4);
      short8 pk;
      pk[0]=(short)f2bf(v0[0]); pk[1]=(short)f2bf(v0[1]); pk[2]=(short)f2bf(v0[2]); pk[3]=(short)f2bf(v0[3]);
      pk[4]=(short)f2bf(v1[0]); pk[5]=(short)f2bf(v1[1]); pk[6]=(short)f2bf(v1[2]); pk[7]=(short)f2bf(v1[3]);
      int off = (r*128 + sx*16) ^ ((r&7)<<4);
      *(short8*)((char*)As + off) = pk;
    }
    #pragma unroll
    for (int i=0;i<4;i++){
      int u = i*256 + tid; int r = u>>3, sx = u&7;
      const float* sp = W_enc + (size_t)r*D_ + kb + sx*8;
      f32x4 v0 = *(const f32x4*)sp;
      f32x4 v1 = *(const f32x4*)(sp+4);
      short8 pk;
      pk[0]=(short)f2bf(v0[0]); pk[1]=(short)f2bf(v0[1]); pk[2]=(short)f2bf(v0[2]); pk[3]=(short)f2bf(v0[3]);
      pk[4]=(short)f2bf(v1[0]); pk[5]=(short)f2bf(v1[1]); pk[6]=(short)f2bf(v1[2]); pk[7]=(short)f2bf(v1[3]);
      int off = (r*128 + sx*16) ^ ((r&7)<<4);
      *(short8*)((char*)Bs + off) = pk;
    }
    __syncthreads();
    #pragma unroll
    for (int kk=0;kk<2;kk++){
      short8 af[2];
      #pragma unroll
      for (int mi=0;mi<2;mi++){
        int r = 32*w + mi*16 + l15;
        int off = (r*128 + kk*64 + lq*16) ^ ((r&7)<<4);
        af[mi] = *(const short8*)((const char*)As + off);
      }
      #pragma unroll
      for (int nf=0;nf<8;nf++){
        int r = nf*16 + l15;
        int off = (r*128 + kk*64 + lq*16) ^ ((r&7)<<4);
        short8 bfr = *(const short8*)((const char*)Bs + off);
        #pragma unroll
        for (int mi=0;mi<2;mi++)
          acc[mi*8+nf] = __builtin_amdgcn_mfma_f32_16x16x32_bf16(af[mi], bfr, acc[mi*8+nf], 0,0,0);
      }
    }
  }
  #pragma unroll
  for (int mi=0;mi<2;mi++){
    #pragma unroll
    for (int nf=0;nf<8;nf++){
      int col = nf*16 + l15;
      float be = bes[col];
      #pragma unroll
      for (int j=0;j<4;j++){
        int bt = m0 + 32*w + mi*16 + lq*4 + j;
        int b = bt >> 6, tt = bt & 63;
        int gg = b >> 7, rg = (b >> 5) & 3, l31b = b & 31;
        int kw = col >> 4, l5b = (col >> 3) & 1, ee = col & 7;
        size_t byteoff = ((((size_t)tt*32 + gg)*32 + rg*8 + kw) << 10)
                       + (l31b + 32*l5b)*16 + ee*2;
        *(unsigned short*)((char*)encF + byteoff) = f2bf(tanh_(acc[mi*8+nf][j] + be));
      }
    }
  }
}

// ---------------------------------------------------------------------------
// Gate-split LSTM recurrence, LDS-resident weights, FENCE-FREE exchange:
// all cross-block data (h frags + flag) moves via relaxed agent-scope atomics
// (device coherence point; no L2 invalidate/writeback instructions emitted).
// Ordering: producer h-stores drain at __syncthreads (vmcnt(0) before
// s_barrier), then tid0 posts flag; consumer sees flag -> barrier -> atomic
// h-loads. Structure/layout identical to R12 otherwise.
// ---------------------------------------------------------------------------
__global__ void rec_kernel(
    const unsigned short* __restrict__ encF,
    const unsigned short* __restrict__ Wf,
    const float* __restrict__ biasc,
    const float* __restrict__ x,
    unsigned short* __restrict__ hgF,     // [2][32][4][16][512] bf16 frags
    int* __restrict__ cnt,                // 32 x (128B line)
    unsigned short* __restrict__ psq,     // [63][8][4096] bf16
    float* __restrict__ out_hn,
    float* __restrict__ out_ldim,
    float* __restrict__ out_ldt){
  extern __shared__ char smem[];
  char* wlds   = smem;                    // 96 KB weight A-frags
  char* hstage = smem + 98304;            // 128 rows x 80 B (bf16 h), 10240 B
  const int tid = threadIdx.x, lane = tid & 63, w = tid >> 6;
  const int l31 = lane & 31, l5 = lane >> 5;
  const int s  = blockIdx.x >> 5;
  const int g  = blockIdx.x & 31;
  const int b0 = g * 128;
  const int bg = w & 3, np = w >> 2;

  // weights -> LDS (coalesced, once)
  {
    const short8* src = (const short8*)(Wf + (size_t)s*49152);
    short8* dst = (short8*)wlds;
    for (int i = tid; i < 6144; i += 512) dst[i] = src[i];
  }

  float biasr[2][16];
  #pragma unroll
  for (int n=0;n<2;n++)
    #pragma unroll
    for (int reg=0;reg<16;reg++){
      int q = reg & 3, hl = 2*(reg>>2) + l5;
      int h = s*32 + (np*2+n)*8 + hl;
      biasr[n][reg] = biasc[h*4 + q];
    }

  const char* abase0 = wlds + (((np*2+0)*24) << 10) + lane*16;  // + ks<<10
  const char* abase1 = wlds + (((np*2+1)*24) << 10) + lane*16;
  const char* ebase  = (const char*)encF + ((size_t)(g*32 + bg*8) << 10) + lane*16;
  const char* hbase  = (const char*)hgF  + ((size_t)((g*4 + bg)*16) << 10) + lane*16;
  char* hgFw = (char*)hgF + ((size_t)(((g*4 + (w>>1))*16) + s*2 + (w&1)) << 10) + lane*16;
  const int hsrd = ((w>>1)*32 + l31)*80 + (w&1)*32 + l5*16;    // LDS byte

  float c[8];
  #pragma unroll
  for (int i=0;i<8;i++) c[i] = 0.f;
  f32x4 ldacc[2];
  ldacc[0] = (f32x4)0.f; ldacc[1] = (f32x4)0.f;

  __syncthreads();   // wlds ready

  for (int t=0; t<T_; ++t){
    // ---- wait for group (all 8 slices posted h(t)); relaxed spin ----
    if (tid == 0 && t > 0){
      const int target = 8*t;
      int guard = 0;
      while (__hip_atomic_load(cnt + g*32, __ATOMIC_RELAXED,
                               __HIP_MEMORY_SCOPE_AGENT) < target){
        if (++guard > (1<<20)) break;     // bail -> wrong result, not a hang
        __builtin_amdgcn_s_sleep(2);
      }
    }
    __syncthreads();

    // prefetch x stripes (normal nt loads; read-only input)
    f32x4 xv[2];
    if (t < T_-1){
      #pragma unroll
      for (int r8=0;r8<2;r8++){
        int row = w*16 + r8*8 + (lane>>3);
        xv[r8] = ntload4f(x + (((size_t)(b0+row)*T_ + t+1)*D_ + s*32 + (lane&7)*4));
      }
    }

    // ---- h B-frags via relaxed agent atomic loads (coherent, no fences) ----
    const char* ht = hbase + ((size_t)(t&1) << 21);
    short8 hfr[16];
    #pragma unroll
    for (int ks=0;ks<16;++ks){
      const unsigned int* p = (const unsigned int*)(ht + ((size_t)ks<<10));
      union { unsigned int u[4]; short8 sv; } cv;
      cv.u[0] = __hip_atomic_load(p+0, __ATOMIC_RELAXED, __HIP_MEMORY_SCOPE_AGENT);
      cv.u[1] = __hip_atomic_load(p+1, __ATOMIC_RELAXED, __HIP_MEMORY_SCOPE_AGENT);
      cv.u[2] = __hip_atomic_load(p+2, __ATOMIC_RELAXED, __HIP_MEMORY_SCOPE_AGENT);
      cv.u[3] = __hip_atomic_load(p+3, __ATOMIC_RELAXED, __HIP_MEMORY_SCOPE_AGENT);
      hfr[ks] = cv.sv;
    }

    // ---- MFMA: enc part (K=128, L2-cached normal loads), then h part ----
    const char* et = ebase + ((size_t)t << 20);
    f32x16 a0 = (f32x16)0.f, a1 = (f32x16)0.f;
    #pragma unroll
    for (int ks=0; ks<8; ++ks){
      short8 bb = *(const short8*)(et + ((size_t)ks<<10));
      short8 A0 = *(const short8*)(abase0 + (ks<<10));
      short8 A1 = *(const short8*)(abase1 + (ks<<10));
      a0 = __builtin_amdgcn_mfma_f32_32x32x16_bf16(A0, bb, a0, 0,0,0);
      a1 = __builtin_amdgcn_mfma_f32_32x32x16_bf16(A1, bb, a1, 0,0,0);
    }
    #pragma unroll
    for (int ks=0; ks<16; ++ks){
      short8 A0 = *(const short8*)(abase0 + ((8+ks)<<10));
      short8 A1 = *(const short8*)(abase1 + ((8+ks)<<10));
      a0 = __builtin_amdgcn_mfma_f32_32x32x16_bf16(A0, hfr[ks], a0, 0,0,0);
      a1 = __builtin_amdgcn_mfma_f32_32x32x16_bf16(A1, hfr[ks], a1, 0,0,0);
    }

    // ---- pointwise: lane owns batch row bg*32+l31, 8 cells ----
    const int prow = bg*32 + l31;
    #pragma unroll
    for (int n=0;n<2;n++){
      #pragma unroll
      for (int r2=0;r2<4;r2++){
        float g0,g1,g2,g3;
        if (n==0){ g0=a0[r2*4+0]; g1=a0[r2*4+1]; g2=a0[r2*4+2]; g3=a0[r2*4+3]; }
        else     { g0=a1[r2*4+0]; g1=a1[r2*4+1]; g2=a1[r2*4+2]; g3=a1[r2*4+3]; }
        float gi = sigm_(g0 + biasr[n][r2*4+0]);
        float gf = sigm_(g1 + biasr[n][r2*4+1]);
        float gg = tanh_(g2 + biasr[n][r2*4+2]);
        float go = sigm_(g3 + biasr[n][r2*4+3]);
        float cn = gf*c[n*4+r2] + gi*gg;
        c[n*4+r2] = cn;
        float hn = go * tanh_(cn);
        int hh = (np*2+n)*8 + 2*r2 + l5;
        *(unsigned short*)(hstage + prow*80 + hh*2) = f2bf(hn);
      }
    }
    __syncthreads();   // hstage complete

    // ---- repack h -> hgF[(t+1)&1] via relaxed agent atomic stores ----
    if (t < T_-1){
      short8 hv = *(const short8*)(hstage + hsrd);
      unsigned int* dst = (unsigned int*)(hgFw + ((size_t)((t+1)&1) << 21));
      union { short8 sv; unsigned int u[4]; } cv; cv.sv = hv;
      __hip_atomic_store(dst+0, cv.u[0], __ATOMIC_RELAXED, __HIP_MEMORY_SCOPE_AGENT);
      __hip_atomic_store(dst+1, cv.u[1], __ATOMIC_RELAXED, __HIP_MEMORY_SCOPE_AGENT);
      __hip_atomic_store(dst+2, cv.u[2], __ATOMIC_RELAXED, __HIP_MEMORY_SCOPE_AGENT);
      __hip_atomic_store(dst+3, cv.u[3], __ATOMIC_RELAXED, __HIP_MEMORY_SCOPE_AGENT);
    }

    // ---- outputs: full-line ldt + psq partial + ldim accum (or h_n) ----
    #pragma unroll
    for (int r8=0;r8<2;r8++){
      int row = w*16 + r8*8 + (lane>>3);
      u32x2 hb = *(const u32x2*)(hstage + row*80 + (lane&7)*8);
      f32x4 hf;
      hf[0] = bf2f((unsigned short)(hb[0] & 0xFFFFu));
      hf[1] = bf2f((unsigned short)(hb[0] >> 16));
      hf[2] = bf2f((unsigned short)(hb[1] & 0xFFFFu));
      hf[3] = bf2f((unsigned short)(hb[1] >> 16));
      float* ltp = out_ldt + (((size_t)(b0+row)*T_ + t)*D_ + s*32 + (lane&7)*4);
      if (t < T_-1){
        f32x4 d;
        d[0] = fabsf(hf[0] - xv[r8][0]);
        d[1] = fabsf(hf[1] - xv[r8][1]);
        d[2] = fabsf(hf[2] - xv[r8][2]);
        d[3] = fabsf(hf[3] - xv[r8][3]);
        __builtin_nontemporal_store(d, (f32x4*)ltp);
        ldacc[r8] += d;
        float ss = d[0]*d[0] + d[1]*d[1] + d[2]*d[2] + d[3]*d[3];
        ss += __shfl_xor(ss, 1);
        ss += __shfl_xor(ss, 2);
        ss += __shfl_xor(ss, 4);
        if ((lane & 7) == 0)
          psq[((size_t)t*8 + s)*4096 + b0 + row] = f2bf(ss);
      } else {
        __builtin_nontemporal_store((f32x4)0.f, (f32x4*)ltp);
        __builtin_nontemporal_store(hf,
            (f32x4*)(out_hn + ((size_t)(b0+row)*H_ + s*32 + (lane&7)*4)));
      }
    }

    // ---- post: barrier drains all VMEM (vmcnt(0) before s_barrier), then
    // tid0 publishes; relaxed is safe because stores already completed ----
    if (t < T_-1){
      __syncthreads();
      if (tid == 0)
        __hip_atomic_fetch_add(cnt + g*32, 1, __ATOMIC_RELAXED,
                               __HIP_MEMORY_SCOPE_AGENT);
    }
  }

  // epilogue: loss_dim
  const float inv = 1.f/63.f;
  #pragma unroll
  for (int r8=0;r8<2;r8++){
    int row = w*16 + r8*8 + (lane>>3);
    *(f32x4*)(out_ldim + ((size_t)(b0+row)*H_ + s*32 + (lane&7)*4)) = ldacc[r8]*inv;
  }
}

// ---------------------------------------------------------------------------
// final: loss[b] = (1/63) sum_t sqrt(sum_s psq[t][s][b]). grid 16 x 256.
// ---------------------------------------------------------------------------
__global__ __launch_bounds__(256) void final_kernel(
    const unsigned short* __restrict__ psq, float* __restrict__ out_loss){
  const int w = threadIdx.x >> 6, lane = threadIdx.x & 63;
  const int b = (blockIdx.x*4 + w)*64 + lane;
  float lacc = 0.f;
  for (int t=0;t<T_-1;++t){
    float sum = 0.f;
    #pragma unroll
    for (int s=0;s<8;s++) sum += bf2f(psq[((size_t)t*8 + s)*4096 + b]);
    lacc += sqrtf(sum);
  }
  out_loss[b] = lacc * (1.f/63.f);
}

// ---------------------------------------------------------------------------
extern "C" void kernel_launch(void* const* d_in, const int* in_sizes, int n_in,
                              void* d_out, int out_size, void* d_ws, size_t ws_size,
                              hipStream_t stream){
  const float* x     = (const float*)d_in[0];
  const float* W_enc = (const float*)d_in[1];
  const float* b_enc = (const float*)d_in[2];
  const float* W_ih  = (const float*)d_in[3];
  const float* b_ih  = (const float*)d_in[4];
  const float* W_hh  = (const float*)d_in[5];
  const float* b_hh  = (const float*)d_in[6];

  // ws: encF 64MB | Wf 768KB | biasc 4KB | hgF 4MB | cnt 4KB | psq 4MB
  char* ws = (char*)d_ws;
  unsigned short* encF  = (unsigned short*)(ws);                 // 67,108,864
  unsigned short* Wf    = (unsigned short*)(ws + 67108864);      //    786,432
  float*          biasc = (float*)         (ws + 67895296);      //      4,096
  unsigned short* hgF   = (unsigned short*)(ws + 67899392);      //  4,194,304
  int*            cnt   = (int*)           (ws + 72093696);      //      4,096
  unsigned short* psq   = (unsigned short*)(ws + 72097792);      //  4,128,768

  float* out_hn   = (float*)d_out;
  float* out_loss = out_hn  + (size_t)B_*H_;
  float* out_ldim = out_loss + B_;
  float* out_ldt  = out_ldim + (size_t)B_*H_;

  (void)hipFuncSetAttribute((const void*)rec_kernel,
      hipFuncAttributeMaxDynamicSharedMemorySize, 108544);

  init_kernel<<<1536, 256, 0, stream>>>(W_ih, b_ih, W_hh, b_hh, Wf, biasc, hgF, cnt);
  enc_kernel<<<2048, 256, 0, stream>>>(x, W_enc, b_enc, encF);
  rec_kernel<<<256, 512, 108544, stream>>>(encF, Wf, biasc, x, hgF, cnt, psq,
                                           out_hn, out_ldim, out_ldt);
  final_kernel<<<16, 256, 0, stream>>>(psq, out_loss);
}

// Round 14
// 1330.289 us; speedup vs baseline: 2.6432x; 1.0963x over previous
//
#include <hip/hip_runtime.h>

// Problem constants
#define B_  4096
#define T_  64
#define D_  256
#define E_  128
#define H_  256

typedef __attribute__((ext_vector_type(8))) short short8;
typedef __attribute__((ext_vector_type(4))) float f32x4;
typedef __attribute__((ext_vector_type(2))) unsigned int u32x2;

__device__ inline unsigned short f2bf(float f){
  unsigned u = __float_as_uint(f);
  u += 0x7FFFu + ((u >> 16) & 1u);   // RNE
  return (unsigned short)(u >> 16);
}
__device__ inline float sigm_(float x){ return __fdividef(1.f, 1.f + __expf(-x)); }
__device__ inline float tanh_(float x){
  float e = __expf(2.f * fminf(fmaxf(x, -15.f), 15.f));
  return __fdividef(e - 1.f, e + 1.f);
}
__device__ inline short8 ntload8(const unsigned short* p){
  return __builtin_nontemporal_load((const short8*)p);
}
__device__ inline f32x4 ntload4f(const float* p){
  return __builtin_nontemporal_load((const f32x4*)p);
}
// async global->LDS, 16 B per lane (dest wave-uniform base; HW adds lane*16)
__device__ inline void gload_lds16(const void* g, void* l){
  __builtin_amdgcn_global_load_lds(
      (const __attribute__((address_space(1))) unsigned int*)g,
      (__attribute__((address_space(3))) unsigned int*)l, 16, 0, 0);
}

// ---------------------------------------------------------------------------
// init: pack weights in staging order: byte(kk,w,q,lane,e) =
//   kk*65536 + w*4096 + q*1024 + lane*16 + e*2   (kk 0..11, w 0..15, q 0..3)
//     h = w*16 + (lane&15); k = kk*32 + (lane>>4)*8 + e; g = q*256 + h
//     val = k<128 ? W_ih[g][k] : W_hh[g][k-128]
// biasc[h*4+q] = b_ih[q*256+h] + b_hh[q*256+h].  grid 1536 x 256.
// ---------------------------------------------------------------------------
__global__ __launch_bounds__(256) void init_kernel(
    const float* __restrict__ W_ih, const float* __restrict__ b_ih,
    const float* __restrict__ W_hh, const float* __restrict__ b_hh,
    unsigned short* __restrict__ Wf, float* __restrict__ biasc){
  const int idx  = blockIdx.x*256 + threadIdx.x;
  const int e    = idx & 7;
  const int lane = (idx >> 3) & 63;
  const int q    = (idx >> 9) & 3;
  const int w    = (idx >> 11) & 15;
  const int kk   = idx >> 15;
  const int h    = w*16 + (lane & 15);
  const int k    = kk*32 + (lane >> 4)*8 + e;
  const int g    = q*H_ + h;
  float v = (k < E_) ? W_ih[g*E_ + k] : W_hh[g*H_ + (k - E_)];
  Wf[idx] = f2bf(v);
  if (idx < 4*H_){
    int hh = idx >> 2, qq = idx & 3, gg = qq*H_ + hh;
    biasc[idx] = b_ih[gg] + b_hh[gg];
  }
}

// ---------------------------------------------------------------------------
// encT[t][b][e] = bf16(tanh(x @ W_enc^T + b_enc)), MFMA 16x16x32 bf16.
// ---------------------------------------------------------------------------
__global__ __launch_bounds__(256) void enc_kernel(
    const float* __restrict__ x, const float* __restrict__ W_enc,
    const float* __restrict__ b_enc, unsigned short* __restrict__ encT){
  __shared__ unsigned short As[128*64];
  __shared__ unsigned short Bs[128*64];
  __shared__ float bes[128];
  const int tid = threadIdx.x;
  const int lane = tid & 63, w = tid >> 6;
  const int l15 = lane & 15, lq = lane >> 4;
  const int m0 = blockIdx.x * 128;
  if (tid < 128) bes[tid] = b_enc[tid];

  f32x4 acc[16];
  #pragma unroll
  for (int i=0;i<16;i++) acc[i] = (f32x4)0.f;

  for (int kc = 0; kc < 4; ++kc){
    const int kb = kc*64;
    __syncthreads();
    #pragma unroll
    for (int i=0;i<4;i++){
      int u = i*256 + tid; int r = u>>3, sx = u&7;
      const float* sp = x + (size_t)(m0+r)*D_ + kb + sx*8;
      f32x4 v0 = ntload4f(sp);
      f32x4 v1 = ntload4f(sp+4);
      short8 pk;
      pk[0]=(short)f2bf(v0[0]); pk[1]=(short)f2bf(v0[1]); pk[2]=(short)f2bf(v0[2]); pk[3]=(short)f2bf(v0[3]);
      pk[4]=(short)f2bf(v1[0]); pk[5]=(short)f2bf(v1[1]); pk[6]=(short)f2bf(v1[2]); pk[7]=(short)f2bf(v1[3]);
      int off = (r*128 + sx*16) ^ ((r&7)<<4);
      *(short8*)((char*)As + off) = pk;
    }
    #pragma unroll
    for (int i=0;i<4;i++){
      int u = i*256 + tid; int r = u>>3, sx = u&7;
      const float* sp = W_enc + (size_t)r*D_ + kb + sx*8;
      f32x4 v0 = *(const f32x4*)sp;
      f32x4 v1 = *(const f32x4*)(sp+4);
      short8 pk;
      pk[0]=(short)f2bf(v0[0]); pk[1]=(short)f2bf(v0[1]); pk[2]=(short)f2bf(v0[2]); pk[3]=(short)f2bf(v0[3]);
      pk[4]=(short)f2bf(v1[0]); pk[5]=(short)f2bf(v1[1]); pk[6]=(short)f2bf(v1[2]); pk[7]=(short)f2bf(v1[3]);
      int off = (r*128 + sx*16) ^ ((r&7)<<4);
      *(short8*)((char*)Bs + off) = pk;
    }
    __syncthreads();
    #pragma unroll
    for (int kk=0;kk<2;kk++){
      short8 af[2];
      #pragma unroll
      for (int mi=0;mi<2;mi++){
        int r = 32*w + mi*16 + l15;
        int off = (r*128 + kk*64 + lq*16) ^ ((r&7)<<4);
        af[mi] = *(const short8*)((const char*)As + off);
      }
      #pragma unroll
      for (int nf=0;nf<8;nf++){
        int r = nf*16 + l15;
        int off = (r*128 + kk*64 + lq*16) ^ ((r&7)<<4);
        short8 bfr = *(const short8*)((const char*)Bs + off);
        #pragma unroll
        for (int mi=0;mi<2;mi++)
          acc[mi*8+nf] = __builtin_amdgcn_mfma_f32_16x16x32_bf16(af[mi], bfr, acc[mi*8+nf], 0,0,0);
      }
    }
  }
  #pragma unroll
  for (int mi=0;mi<2;mi++){
    #pragma unroll
    for (int nf=0;nf<8;nf++){
      int col = nf*16 + l15;
      float be = bes[col];
      #pragma unroll
      for (int j=0;j<4;j++){
        int bt = m0 + 32*w + mi*16 + lq*4 + j;
        int b = bt >> 6, tt = bt & 63;
        encT[((size_t)tt*B_ + b)*E_ + col] = f2bf(tanh_(acc[mi*8+nf][j] + be));
      }
    }
  }
}

// ---------------------------------------------------------------------------
// Persistent LSTM recurrence, self-paced per-wave weight staging with
// PER-BLOCK CHUNK-PHASE ROTATION: block sweeps chunks rot,rot+1,...,rot+11
// (mod 12), rot = (blockIdx>>3)%12, so the 32 blocks co-resident on an XCD
// hit all 12 chunk regions simultaneously -> all L2 banks active (fixes the
// hot-bank serialization that pinned 4 designs at ~20 us/step).
// Otherwise identical to R11: 256 blocks x 1024 threads, private 2-slot LDS
// ring per wave, counted vmcnt(4), ONE barrier/step.
// ---------------------------------------------------------------------------
__global__ __launch_bounds__(1024) void rec_kernel(
    const unsigned short* __restrict__ encT,
    const unsigned short* __restrict__ Wf,
    const float* __restrict__ biasc,
    const float* __restrict__ x,
    float* __restrict__ out_hn,
    float* __restrict__ out_loss,
    float* __restrict__ out_ldim,
    float* __restrict__ out_ldt){
  extern __shared__ char smem[];       // 147456 B
  char* wring = smem;                  // [16 waves][2 slots][4096 B] = 128 KB
  char* hb0   = smem + 131072;         // h dbuf 0 (8 KB, swizzled)
  char* hb1   = smem + 139264;         // h dbuf 1 (8 KB)

  const int tid = threadIdx.x, lane = tid & 63, w = tid >> 6;
  const int l15 = lane & 15, lq = lane >> 4;
  const int b0 = blockIdx.x * 16;
  const int hw = w*16 + l15;
  const int rot = (blockIdx.x >> 3) % 12;   // chunk-phase rotation

  const f32x4 bias = *(const f32x4*)(biasc + hw*4);

  const char* wsrcw = (const char*)Wf + w*4096 + lane*16;  // + kk*65536 + q*1024
  char* wbase = wring + w*8192;                            // + slot*4096

  const unsigned short* ep = encT + (size_t)(b0 + l15)*E_ + lq*8;
  const int rdb = l15*512 + lq*16;
  const int rsw = (l15 & 7) << 4;

  // write-pass mapping: wave w <-> batch row b0+w; lane <-> h[lane*4..+4)
  const int wp0 = (w*512 + lane*8) ^ ((w&7)<<4);
  const float* xr0 = x + (size_t)(b0+w)*T_*D_ + lane*4;
  float* lt0 = out_ldt + (size_t)(b0+w)*T_*H_ + lane*4;

  float c[4] = {0.f,0.f,0.f,0.f};
  f32x4 ld0 = (f32x4)0.f;
  float la0 = 0.f;

  // prologue: zero hbuf0; stage chunk `rot` into slot 0
  if (tid < 512) *(short8*)(hb0 + tid*16) = (short8)(short)0;
  #pragma unroll
  for (int q=0;q<4;q++)
    gload_lds16(wsrcw + (size_t)rot*65536 + q*1024, wbase + q*1024);
  __syncthreads();

  for (int t=0; t<T_; ++t){
    char* rb = (t & 1) ? hb1 : hb0;
    char* wb = (t & 1) ? hb0 : hb1;

    // per-step A-frags (enc) + x prefetch for write-pass
    short8 ae[4];
    #pragma unroll
    for (int kk=0;kk<4;kk++) ae[kk] = ntload8(ep + (size_t)t*B_*E_ + kk*32);
    f32x4 xw0 = (f32x4)0.f;
    if (t < T_-1) xw0 = ntload4f(xr0 + (size_t)(t+1)*D_);

    f32x4 acc[4];
    #pragma unroll
    for (int q=0;q<4;q++) acc[q] = (f32x4)0.f;

    #pragma unroll
    for (int pos=0; pos<12; pos++){
      // chunk values are rotated; v (SGPR-uniform) = chunk consumed at pos
      int v  = rot + pos;      if (v  >= 12) v  -= 12;
      int vn = rot + pos + 1;  if (vn >= 12) vn -= 12;  // wraps to rot @ pos 11
      // issue next chunk into the other slot
      char* sl = wbase + ((pos+1)&1)*4096;
      #pragma unroll
      for (int q=0;q<4;q++)
        gload_lds16(wsrcw + (size_t)vn*65536 + q*1024, sl + q*1024);
      // wait until chunk at `pos`'s 4 loads landed (4 newer stay in flight)
      asm volatile("s_waitcnt vmcnt(4)" ::: "memory");
      __builtin_amdgcn_sched_barrier(0);
      // consume: A-frag by uniform if-chain (no runtime reg-array indexing)
      const char* cl = wbase + (pos&1)*4096 + lane*16;
      short8 a;
      if (v >= 4)      a = *(const short8*)(rb + ((rdb + (v-4)*64) ^ rsw));
      else if (v == 0) a = ae[0];
      else if (v == 1) a = ae[1];
      else if (v == 2) a = ae[2];
      else             a = ae[3];
      #pragma unroll
      for (int q=0;q<4;q++){
        short8 bq = *(const short8*)(cl + q*1024);
        acc[q] = __builtin_amdgcn_mfma_f32_16x16x32_bf16(a, bq, acc[q], 0,0,0);
      }
    }

    // pointwise: lane owns h=hw, rows lq*4+j
    #pragma unroll
    for (int j=0;j<4;j++){
      float gi = sigm_(acc[0][j] + bias[0]);
      float gf = sigm_(acc[1][j] + bias[1]);
      float gg = tanh_(acc[2][j] + bias[2]);
      float go = sigm_(acc[3][j] + bias[3]);
      float cn = gf*c[j] + gi*gg;
      c[j] = cn;
      float hn = go * tanh_(cn);
      const int row = lq*4 + j;
      *(unsigned short*)(wb + ((row*512 + hw*2) ^ ((row&7)<<4))) = f2bf(hn);
      if (t == T_-1)
        __builtin_nontemporal_store(hn, out_hn + (size_t)(b0+row)*H_ + hw);
    }
    __syncthreads();   // h(t+1) visible; sole block-wide rendezvous per step

    // write-pass: full-line coalesced ldt stores + fused reductions
    if (t < T_-1){
      u32x2 hv0 = *(const u32x2*)(wb + wp0);
      f32x4 d0;
      d0[0] = fabsf(__uint_as_float((hv0[0] & 0xFFFFu) << 16) - xw0[0]);
      d0[1] = fabsf(__uint_as_float(hv0[0] & 0xFFFF0000u)     - xw0[1]);
      d0[2] = fabsf(__uint_as_float((hv0[1] & 0xFFFFu) << 16) - xw0[2]);
      d0[3] = fabsf(__uint_as_float(hv0[1] & 0xFFFF0000u)     - xw0[3]);
      __builtin_nontemporal_store(d0, (f32x4*)(lt0 + (size_t)t*H_));
      ld0 += d0;
      float s0 = d0[0]*d0[0] + d0[1]*d0[1] + d0[2]*d0[2] + d0[3]*d0[3];
      #pragma unroll
      for (int off=32; off; off>>=1) s0 += __shfl_xor(s0, off);
      la0 += sqrtf(s0);
    } else {
      __builtin_nontemporal_store((f32x4)0.f, (f32x4*)(lt0 + (size_t)t*H_));
    }
  }

  // epilogue: loss_dim and loss for row b0+w
  const float inv = 1.f/(float)(T_-1);
  *(f32x4*)(out_ldim + (size_t)(b0+w)*H_ + lane*4) = ld0*inv;
  if (lane == 0) out_loss[b0+w] = la0*inv;
}

// ---------------------------------------------------------------------------
extern "C" void kernel_launch(void* const* d_in, const int* in_sizes, int n_in,
                              void* d_out, int out_size, void* d_ws, size_t ws_size,
                              hipStream_t stream){
  const float* x     = (const float*)d_in[0];
  const float* W_enc = (const float*)d_in[1];
  const float* b_enc = (const float*)d_in[2];
  const float* W_ih  = (const float*)d_in[3];
  const float* b_ih  = (const float*)d_in[4];
  const float* W_hh  = (const float*)d_in[5];
  const float* b_hh  = (const float*)d_in[6];

  // workspace: encT 64 MB | Wf 768 KB | biasc 4 KB
  char* ws = (char*)d_ws;
  unsigned short* encT  = (unsigned short*)(ws);                 // 67,108,864
  unsigned short* Wf    = (unsigned short*)(ws + 67108864);      //    786,432
  float*          biasc = (float*)        (ws + 67895296);       //      4,096

  float* out_hn   = (float*)d_out;
  float* out_loss = out_hn  + (size_t)B_*H_;
  float* out_ldim = out_loss + B_;
  float* out_ldt  = out_ldim + (size_t)B_*H_;

  (void)hipFuncSetAttribute((const void*)rec_kernel,
      hipFuncAttributeMaxDynamicSharedMemorySize, 147456);

  init_kernel<<<1536, 256, 0, stream>>>(W_ih, b_ih, W_hh, b_hh, Wf, biasc);
  enc_kernel<<<2048, 256, 0, stream>>>(x, W_enc, b_enc, encT);
  rec_kernel<<<256, 1024, 147456, stream>>>(encT, Wf, biasc, x, out_hn,
                                            out_loss, out_ldim, out_ldt);
}

// Round 15
// 1023.991 us; speedup vs baseline: 3.4338x; 1.2991x over previous
//
#include <hip/hip_runtime.h>

// Problem constants
#define B_  4096
#define T_  64
#define D_  256
#define E_  128
#define H_  256

typedef __attribute__((ext_vector_type(8))) short short8;
typedef __attribute__((ext_vector_type(4))) float f32x4;
typedef __attribute__((ext_vector_type(16))) float f32x16;
typedef __attribute__((ext_vector_type(2))) unsigned int u32x2;

__device__ inline unsigned short f2bf(float f){
  unsigned u = __float_as_uint(f);
  u += 0x7FFFu + ((u >> 16) & 1u);   // RNE
  return (unsigned short)(u >> 16);
}
__device__ inline float bf2f(unsigned short v){
  return __uint_as_float(((unsigned)v) << 16);
}
__device__ inline float sigm_(float x){ return __fdividef(1.f, 1.f + __expf(-x)); }
__device__ inline float tanh_(float x){
  float e = __expf(2.f * fminf(fmaxf(x, -15.f), 15.f));
  return __fdividef(e - 1.f, e + 1.f);
}
__device__ inline short8 ntload8(const unsigned short* p){
  return __builtin_nontemporal_load((const short8*)p);
}
__device__ inline f32x4 ntload4f(const float* p){
  return __builtin_nontemporal_load((const f32x4*)p);
}

// ---------------------------------------------------------------------------
// init: pack weights as 32x32x16 MFMA A-fragments per slice (R12/R13 layout,
// HW-verified): Wf[((s*4+nf)*24 + ks)*512 + l*8 + e]
//   r = l&31: q = r&3, hl = r>>2; h = s*32 + nf*8 + hl
//   k = ks*16 + (l>>5)*8 + e; g = q*256 + h
//   val = k<128 ? W_ih[g][k] : W_hh[g][k-128]
// biasc[h*4+q]; zero hgF buf0 (2 MB); zero cnt lines.  grid 1536 x 256.
// ---------------------------------------------------------------------------
__global__ __launch_bounds__(256) void init_kernel(
    const float* __restrict__ W_ih, const float* __restrict__ b_ih,
    const float* __restrict__ W_hh, const float* __restrict__ b_hh,
    unsigned short* __restrict__ Wf, float* __restrict__ biasc,
    unsigned short* __restrict__ hgF, int* __restrict__ cnt){
  const int idx  = blockIdx.x*256 + threadIdx.x;
  const int e    = idx & 7;
  const int l    = (idx >> 3) & 63;
  const int fk   = idx >> 9;          // (s*4+nf)*24 + ks
  const int ks   = fk % 24;
  const int nfs  = fk / 24;
  const int nf   = nfs & 3;
  const int s    = nfs >> 2;
  const int r    = l & 31;
  const int q    = r & 3;
  const int hl   = r >> 2;
  const int h    = s*32 + nf*8 + hl;
  const int k    = ks*16 + (l >> 5)*8 + e;
  const int g    = q*H_ + h;
  float v = (k < E_) ? W_ih[g*E_ + k] : W_hh[g*H_ + (k - E_)];
  Wf[idx] = f2bf(v);
  if (idx < 4*H_){
    int hh = idx >> 2, qq = idx & 3, gg = qq*H_ + hh;
    biasc[idx] = b_ih[gg] + b_hh[gg];
  }
  if (idx < 262144) ((unsigned long long*)hgF)[idx] = 0ull;   // buf0 = 2 MB zeros
  if (idx < 1024) cnt[idx] = 0;
}

// ---------------------------------------------------------------------------
// enc: encF = bf16(tanh(x @ W_enc^T + b_enc)) in B-fragment order (R12).
// ---------------------------------------------------------------------------
__global__ __launch_bounds__(256) void enc_kernel(
    const float* __restrict__ x, const float* __restrict__ W_enc,
    const float* __restrict__ b_enc, unsigned short* __restrict__ encF){
  __shared__ unsigned short As[128*64];
  __shared__ unsigned short Bs[128*64];
  __shared__ float bes[128];
  const int tid = threadIdx.x;
  const int lane = tid & 63, w = tid >> 6;
  const int l15 = lane & 15, lq = lane >> 4;
  const int m0 = blockIdx.x * 128;
  if (tid < 128) bes[tid] = b_enc[tid];

  f32x4 acc[16];
  #pragma unroll
  for (int i=0;i<16;i++) acc[i] = (f32x4)0.f;

  for (int kc = 0; kc < 4; ++kc){
    const int kb = kc*64;
    __syncthreads();
    #pragma unroll
    for (int i=0;i<4;i++){
      int u = i*256 + tid; int r = u>>3, sx = u&7;
      const float* sp = x + (size_t)(m0+r)*D_ + kb + sx*8;
      f32x4 v0 = ntload4f(sp);
      f32x4 v1 = ntload4f(sp+4);
      short8 pk;
      pk[0]=(short)f2bf(v0[0]); pk[1]=(short)f2bf(v0[1]); pk[2]=(short)f2bf(v0[2]); pk[3]=(short)f2bf(v0[3]);
      pk[4]=(short)f2bf(v1[0]); pk[5]=(short)f2bf(v1[1]); pk[6]=(short)f2bf(v1[2]); pk[7]=(short)f2bf(v1[3]);
      int off = (r*128 + sx*16) ^ ((r&7)<<4);
      *(short8*)((char*)As + off) = pk;
    }
    #pragma unroll
    for (int i=0;i<4;i++){
      int u = i*256 + tid; int r = u>>3, sx = u&7;
      const float* sp = W_enc + (size_t)r*D_ + kb + sx*8;
      f32x4 v0 = *(const f32x4*)sp;
      f32x4 v1 = *(const f32x4*)(sp+4);
      short8 pk;
      pk[0]=(short)f2bf(v0[0]); pk[1]=(short)f2bf(v0[1]); pk[2]=(short)f2bf(v0[2]); pk[3]=(short)f2bf(v0[3]);
      pk[4]=(short)f2bf(v1[0]); pk[5]=(short)f2bf(v1[1]); pk[6]=(short)f2bf(v1[2]); pk[7]=(short)f2bf(v1[3]);
      int off = (r*128 + sx*16) ^ ((r&7)<<4);
      *(short8*)((char*)Bs + off) = pk;
    }
    __syncthreads();
    #pragma unroll
    for (int kk=0;kk<2;kk++){
      short8 af[2];
      #pragma unroll
      for (int mi=0;mi<2;mi++){
        int r = 32*w + mi*16 + l15;
        int off = (r*128 + kk*64 + lq*16) ^ ((r&7)<<4);
        af[mi] = *(const short8*)((const char*)As + off);
      }
      #pragma unroll
      for (int nf=0;nf<8;nf++){
        int r = nf*16 + l15;
        int off = (r*128 + kk*64 + lq*16) ^ ((r&7)<<4);
        short8 bfr = *(const short8*)((const char*)Bs + off);
        #pragma unroll
        for (int mi=0;mi<2;mi++)
          acc[mi*8+nf] = __builtin_amdgcn_mfma_f32_16x16x32_bf16(af[mi], bfr, acc[mi*8+nf], 0,0,0);
      }
    }
  }
  #pragma unroll
  for (int mi=0;mi<2;mi++){
    #pragma unroll
    for (int nf=0;nf<8;nf++){
      int col = nf*16 + l15;
      float be = bes[col];
      #pragma unroll
      for (int j=0;j<4;j++){
        int bt = m0 + 32*w + mi*16 + lq*4 + j;
        int b = bt >> 6, tt = bt & 63;
        int gg = b >> 7, rg = (b >> 5) & 3, l31b = b & 31;
        int kw = col >> 4, l5b = (col >> 3) & 1, ee = col & 7;
        size_t byteoff = ((((size_t)tt*32 + gg)*32 + rg*8 + kw) << 10)
                       + (l31b + 32*l5b)*16 + ee*2;
        *(unsigned short*)((char*)encF + byteoff) = f2bf(tanh_(acc[mi*8+nf][j] + be));
      }
    }
  }
}

// ---------------------------------------------------------------------------
// Gate-split LSTM recurrence, R13 rebuilt for latency tolerance:
// 256 blocks x 1024 threads (16 waves, 4/SIMD). block = (s = bx>>5 slice,
// g = bx&31 batch-group of 128 rows). Weights 96 KB in LDS (once).
// Per step: [prefetch enc/x] -> spin(flag>=8t)+bar -> issue 16 atomic-dword
// h-frag loads (staged ONCE to 64 KB LDS; no redundancy) overlapped with
// enc-part MFMA -> bar -> h-part MFMA (B from LDS) -> bar -> pointwise ->
// bar -> repack 8 frags to hgF (atomic stores) -> bar -> post flag ->
// write-pass (ldt/psq/ldim) AFTER post so producers lead consumers.
// ---------------------------------------------------------------------------
__global__ __launch_bounds__(1024) void rec_kernel(
    const unsigned short* __restrict__ encF,
    const unsigned short* __restrict__ Wf,
    const float* __restrict__ biasc,
    const float* __restrict__ x,
    unsigned short* __restrict__ hgF,     // 2 bufs x [32 g][4 bg][16 ks][1 KB]
    int* __restrict__ cnt,                // 32 x (128B line)
    unsigned short* __restrict__ psq,     // [63][8][4096] bf16
    float* __restrict__ out_hn,
    float* __restrict__ out_ldim,
    float* __restrict__ out_ldt){
  extern __shared__ char smem[];
  char* wlds = smem;                      // 96 KB weight A-frags
  char* hbuf = smem + 98304;              // 64 KB [128 rows][256 h] bf16, swizzled
  const int tid = threadIdx.x, lane = tid & 63, w = tid >> 6;
  const int l31 = lane & 31, l5 = lane >> 5;
  const int s  = blockIdx.x >> 5;
  const int g  = blockIdx.x & 31;
  const int b0 = g * 128;
  const int nf = w & 3, bg = w >> 2;

  // weights -> LDS (coalesced, once)
  {
    const short8* src = (const short8*)(Wf + (size_t)s*49152);
    short8* dst = (short8*)wlds;
    for (int i = tid; i < 6144; i += 1024) dst[i] = src[i];
  }

  float biasr[16];
  #pragma unroll
  for (int reg=0; reg<16; ++reg){
    int q = reg & 3, hl = nf*8 + 2*(reg>>2) + l5;
    biasr[reg] = biasc[(s*32 + hl)*4 + q];
  }

  const char* abase = wlds + ((nf*24) << 10) + lane*16;                  // + ks<<10
  const char* ebase = (const char*)encF + (((size_t)(g*32 + bg*8)) << 10) + lane*16;

  const int myrow = bg*32 + l31;
  const int swz   = (l31 & 7) << 4;
  const int hrd   = myrow*512 + l5*16;      // + ks*32, ^swz

  // write-pass mapping: wave w -> rows w*8..w*8+8, lane&7 -> h-chunk
  const int row2  = w*8 + (lane >> 3);
  const int swz2  = (row2 & 7) << 4;
  const int hord  = row2*512 + s*64 + (lane & 7)*8;   // ^swz2
  const float* xr = x + (size_t)(b0+row2)*T_*D_ + s*32 + (lane&7)*4;
  float* ltr = out_ldt + (size_t)(b0+row2)*T_*H_ + s*32 + (lane&7)*4;

  float c[4] = {0.f,0.f,0.f,0.f};
  f32x4 ldim = (f32x4)0.f;

  __syncthreads();   // wlds ready

  for (int t=0; t<T_; ++t){
    // A. prefetch enc frags + x stripe (flag-independent)
    short8 ef[8];
    #pragma unroll
    for (int kw=0;kw<8;kw++)
      ef[kw] = ntload8((const unsigned short*)(ebase + ((size_t)t<<20) + (kw<<10)));
    f32x4 xv = (f32x4)0.f;
    if (t < T_-1) xv = ntload4f(xr + (size_t)(t+1)*D_);

    // C. spin (tid0, relaxed) + barrier
    if (tid == 0 && t > 0){
      int guard = 0;
      while (__hip_atomic_load(cnt + g*32, __ATOMIC_RELAXED,
                               __HIP_MEMORY_SCOPE_AGENT) < 8*t){
        if (++guard > (1<<20)) break;   // bail -> wrong result, not a hang
        __builtin_amdgcn_s_sleep(2);
      }
    }
    __syncthreads();

    // D-issue: wave stages frags f = w*4+i (16 atomic dword loads)
    unsigned int hv[4][4];
    const size_t cbuf = ((size_t)(t&1)) << 21;
    #pragma unroll
    for (int i=0;i<4;i++){
      int f = w*4 + i;
      int bgf = f >> 4, ksf = f & 15;
      const unsigned int* p = (const unsigned int*)((const char*)hgF + cbuf
                            + (((size_t)((g*4 + bgf)*16 + ksf)) << 10) + lane*16);
      #pragma unroll
      for (int d=0; d<4; d++)
        hv[i][d] = __hip_atomic_load(p+d, __ATOMIC_RELAXED, __HIP_MEMORY_SCOPE_AGENT);
    }

    // B. enc-part MFMA (overlaps exchange-load latency)
    f32x16 a = (f32x16)0.f;
    #pragma unroll
    for (int ks=0; ks<8; ++ks){
      short8 A = *(const short8*)(abase + (ks<<10));
      a = __builtin_amdgcn_mfma_f32_32x32x16_bf16(A, ef[ks], a, 0,0,0);
    }

    // D-write: staged frags -> hbuf (swizzled [row][hk])
    #pragma unroll
    for (int i=0;i<4;i++){
      int f = w*4 + i;
      int bgf = f >> 4, ksf = f & 15;
      int row = bgf*32 + l31;
      union { unsigned int u[4]; short8 sv; } cv;
      cv.u[0]=hv[i][0]; cv.u[1]=hv[i][1]; cv.u[2]=hv[i][2]; cv.u[3]=hv[i][3];
      *(short8*)(hbuf + ((row*512 + ksf*32 + l5*16) ^ ((row&7)<<4))) = cv.sv;
    }
    __syncthreads();   // bar1: hbuf staged

    // E. h-part MFMA (B from LDS)
    #pragma unroll
    for (int ks=0; ks<16; ++ks){
      short8 A  = *(const short8*)(abase + ((8+ks)<<10));
      short8 Bv = *(const short8*)(hbuf + ((hrd + ks*32) ^ swz));
      a = __builtin_amdgcn_mfma_f32_32x32x16_bf16(A, Bv, a, 0,0,0);
    }
    __syncthreads();   // bar2: all hbuf reads done

    // F. pointwise -> h(t) overlay into hbuf cols s*32..s*32+32
    #pragma unroll
    for (int r2=0; r2<4; ++r2){
      float gi = sigm_(a[r2*4+0] + biasr[r2*4+0]);
      float gf = sigm_(a[r2*4+1] + biasr[r2*4+1]);
      float gg = tanh_(a[r2*4+2] + biasr[r2*4+2]);
      float go = sigm_(a[r2*4+3] + biasr[r2*4+3]);
      float cn = gf*c[r2] + gi*gg;
      c[r2] = cn;
      float hn = go * tanh_(cn);
      int hl = nf*8 + 2*r2 + l5;
      *(unsigned short*)(hbuf + ((myrow*512 + (s*32+hl)*2) ^ swz)) = f2bf(hn);
    }
    __syncthreads();   // bar3: overlay complete

    // G. repack 8 frags -> hgF[(t+1)&1] (atomic stores), then post flag
    if (t < T_-1){
      if (w < 8){
        int bgr = w >> 1, kwl = w & 1;
        int rrow = bgr*32 + l31;
        short8 hv8 = *(const short8*)(hbuf +
            ((rrow*512 + s*64 + kwl*32 + l5*16) ^ ((rrow&7)<<4)));
        union { short8 sv; unsigned int u[4]; } cv; cv.sv = hv8;
        unsigned int* dstp = (unsigned int*)((char*)hgF
            + (((size_t)((t+1)&1))<<21)
            + (((size_t)((g*4 + bgr)*16 + s*2 + kwl)) << 10) + lane*16);
        #pragma unroll
        for (int d=0; d<4; d++)
          __hip_atomic_store(dstp+d, cv.u[d], __ATOMIC_RELAXED,
                             __HIP_MEMORY_SCOPE_AGENT);
      }
      __syncthreads();  // bar4: all stores drained (vmcnt0 before s_barrier)
      if (tid == 0)
        __hip_atomic_fetch_add(cnt + g*32, 1, __ATOMIC_RELAXED,
                               __HIP_MEMORY_SCOPE_AGENT);
    }

    // H. write-pass (after post: producers lead consumers)
    u32x2 hb = *(const u32x2*)(hbuf + (hord ^ swz2));
    f32x4 hf;
    hf[0] = bf2f((unsigned short)(hb[0] & 0xFFFFu));
    hf[1] = bf2f((unsigned short)(hb[0] >> 16));
    hf[2] = bf2f((unsigned short)(hb[1] & 0xFFFFu));
    hf[3] = bf2f((unsigned short)(hb[1] >> 16));
    float* ltp = ltr + (size_t)t*H_;
    if (t < T_-1){
      f32x4 d;
      d[0] = fabsf(hf[0] - xv[0]);
      d[1] = fabsf(hf[1] - xv[1]);
      d[2] = fabsf(hf[2] - xv[2]);
      d[3] = fabsf(hf[3] - xv[3]);
      __builtin_nontemporal_store(d, (f32x4*)ltp);
      ldim += d;
      float ss = d[0]*d[0] + d[1]*d[1] + d[2]*d[2] + d[3]*d[3];
      ss += __shfl_xor(ss, 1);
      ss += __shfl_xor(ss, 2);
      ss += __shfl_xor(ss, 4);
      if ((lane & 7) == 0)
        psq[((size_t)t*8 + s)*4096 + b0 + row2] = f2bf(ss);
    } else {
      __builtin_nontemporal_store((f32x4)0.f, (f32x4*)ltp);
      __builtin_nontemporal_store(hf,
          (f32x4*)(out_hn + (size_t)(b0+row2)*H_ + s*32 + (lane&7)*4));
    }
  }

  // epilogue: loss_dim
  *(f32x4*)(out_ldim + (size_t)(b0+row2)*H_ + s*32 + (lane&7)*4) = ldim * (1.f/63.f);
}

// ---------------------------------------------------------------------------
// final: loss[b] = (1/63) sum_t sqrt(sum_s psq[t][s][b]). grid 16 x 256.
// ---------------------------------------------------------------------------
__global__ __launch_bounds__(256) void final_kernel(
    const unsigned short* __restrict__ psq, float* __restrict__ out_loss){
  const int w = threadIdx.x >> 6, lane = threadIdx.x & 63;
  const int b = (blockIdx.x*4 + w)*64 + lane;
  float lacc = 0.f;
  for (int t=0;t<T_-1;++t){
    float sum = 0.f;
    #pragma unroll
    for (int s=0;s<8;s++) sum += bf2f(psq[((size_t)t*8 + s)*4096 + b]);
    lacc += sqrtf(sum);
  }
  out_loss[b] = lacc * (1.f/63.f);
}

// ---------------------------------------------------------------------------
extern "C" void kernel_launch(void* const* d_in, const int* in_sizes, int n_in,
                              void* d_out, int out_size, void* d_ws, size_t ws_size,
                              hipStream_t stream){
  const float* x     = (const float*)d_in[0];
  const float* W_enc = (const float*)d_in[1];
  const float* b_enc = (const float*)d_in[2];
  const float* W_ih  = (const float*)d_in[3];
  const float* b_ih  = (const float*)d_in[4];
  const float* W_hh  = (const float*)d_in[5];
  const float* b_hh  = (const float*)d_in[6];

  // ws: encF 64MB | Wf 768KB | biasc 4KB | hgF 4MB | cnt 4KB | psq 4MB
  char* ws = (char*)d_ws;
  unsigned short* encF  = (unsigned short*)(ws);                 // 67,108,864
  unsigned short* Wf    = (unsigned short*)(ws + 67108864);      //    786,432
  float*          biasc = (float*)         (ws + 67895296);      //      4,096
  unsigned short* hgF   = (unsigned short*)(ws + 67899392);      //  4,194,304
  int*            cnt   = (int*)           (ws + 72093696);      //      4,096
  unsigned short* psq   = (unsigned short*)(ws + 72097792);      //  4,128,768

  float* out_hn   = (float*)d_out;
  float* out_loss = out_hn  + (size_t)B_*H_;
  float* out_ldim = out_loss + B_;
  float* out_ldt  = out_ldim + (size_t)B_*H_;

  (void)hipFuncSetAttribute((const void*)rec_kernel,
      hipFuncAttributeMaxDynamicSharedMemorySize, 163840);

  init_kernel<<<1536, 256, 0, stream>>>(W_ih, b_ih, W_hh, b_hh, Wf, biasc, hgF, cnt);
  enc_kernel<<<2048, 256, 0, stream>>>(x, W_enc, b_enc, encF);
  rec_kernel<<<256, 1024, 163840, stream>>>(encF, Wf, biasc, x, hgF, cnt, psq,
                                            out_hn, out_ldim, out_ldt);
  final_kernel<<<16, 256, 0, stream>>>(psq, out_loss);
}

// Round 16
// 823.365 us; speedup vs baseline: 4.2705x; 1.2437x over previous
//
#include <hip/hip_runtime.h>

// Problem constants
#define B_  4096
#define T_  64
#define D_  256
#define E_  128
#define H_  256

typedef __attribute__((ext_vector_type(8))) short short8;
typedef __attribute__((ext_vector_type(4))) float f32x4;
typedef __attribute__((ext_vector_type(16))) float f32x16;
typedef __attribute__((ext_vector_type(2))) unsigned int u32x2;

__device__ inline unsigned short f2bf(float f){
  unsigned u = __float_as_uint(f);
  u += 0x7FFFu + ((u >> 16) & 1u);   // RNE
  return (unsigned short)(u >> 16);
}
__device__ inline float bf2f(unsigned short v){
  return __uint_as_float(((unsigned)v) << 16);
}
__device__ inline float sigm_(float x){ return __fdividef(1.f, 1.f + __expf(-x)); }
__device__ inline float tanh_(float x){
  float e = __expf(2.f * fminf(fmaxf(x, -15.f), 15.f));
  return __fdividef(e - 1.f, e + 1.f);
}
__device__ inline short8 ntload8(const unsigned short* p){
  return __builtin_nontemporal_load((const short8*)p);
}
__device__ inline f32x4 ntload4f(const float* p){
  return __builtin_nontemporal_load((const f32x4*)p);
}

// ---------------------------------------------------------------------------
// init: pack weights as 32x32x16 MFMA A-fragments per slice (R12/R13 layout).
// biasc[h*4+q]; zero hgF buf0 (2 MB); zero cnt (256 x 128B lines).
// ---------------------------------------------------------------------------
__global__ __launch_bounds__(256) void init_kernel(
    const float* __restrict__ W_ih, const float* __restrict__ b_ih,
    const float* __restrict__ W_hh, const float* __restrict__ b_hh,
    unsigned short* __restrict__ Wf, float* __restrict__ biasc,
    unsigned short* __restrict__ hgF, int* __restrict__ cnt){
  const int idx  = blockIdx.x*256 + threadIdx.x;
  const int e    = idx & 7;
  const int l    = (idx >> 3) & 63;
  const int fk   = idx >> 9;          // (s*4+nf)*24 + ks
  const int ks   = fk % 24;
  const int nfs  = fk / 24;
  const int nf   = nfs & 3;
  const int s    = nfs >> 2;
  const int r    = l & 31;
  const int q    = r & 3;
  const int hl   = r >> 2;
  const int h    = s*32 + nf*8 + hl;
  const int k    = ks*16 + (l >> 5)*8 + e;
  const int g    = q*H_ + h;
  float v = (k < E_) ? W_ih[g*E_ + k] : W_hh[g*H_ + (k - E_)];
  Wf[idx] = f2bf(v);
  if (idx < 4*H_){
    int hh = idx >> 2, qq = idx & 3, gg = qq*H_ + hh;
    biasc[idx] = b_ih[gg] + b_hh[gg];
  }
  if (idx < 262144) ((unsigned long long*)hgF)[idx] = 0ull;   // buf0 = 2 MB zeros
  if (idx < 8192) cnt[idx] = 0;
}

// ---------------------------------------------------------------------------
// enc: encF = bf16(tanh(x @ W_enc^T + b_enc)) in B-fragment order (R12).
// ---------------------------------------------------------------------------
__global__ __launch_bounds__(256) void enc_kernel(
    const float* __restrict__ x, const float* __restrict__ W_enc,
    const float* __restrict__ b_enc, unsigned short* __restrict__ encF){
  __shared__ unsigned short As[128*64];
  __shared__ unsigned short Bs[128*64];
  __shared__ float bes[128];
  const int tid = threadIdx.x;
  const int lane = tid & 63, w = tid >> 6;
  const int l15 = lane & 15, lq = lane >> 4;
  const int m0 = blockIdx.x * 128;
  if (tid < 128) bes[tid] = b_enc[tid];

  f32x4 acc[16];
  #pragma unroll
  for (int i=0;i<16;i++) acc[i] = (f32x4)0.f;

  for (int kc = 0; kc < 4; ++kc){
    const int kb = kc*64;
    __syncthreads();
    #pragma unroll
    for (int i=0;i<4;i++){
      int u = i*256 + tid; int r = u>>3, sx = u&7;
      const float* sp = x + (size_t)(m0+r)*D_ + kb + sx*8;
      f32x4 v0 = ntload4f(sp);
      f32x4 v1 = ntload4f(sp+4);
      short8 pk;
      pk[0]=(short)f2bf(v0[0]); pk[1]=(short)f2bf(v0[1]); pk[2]=(short)f2bf(v0[2]); pk[3]=(short)f2bf(v0[3]);
      pk[4]=(short)f2bf(v1[0]); pk[5]=(short)f2bf(v1[1]); pk[6]=(short)f2bf(v1[2]); pk[7]=(short)f2bf(v1[3]);
      int off = (r*128 + sx*16) ^ ((r&7)<<4);
      *(short8*)((char*)As + off) = pk;
    }
    #pragma unroll
    for (int i=0;i<4;i++){
      int u = i*256 + tid; int r = u>>3, sx = u&7;
      const float* sp = W_enc + (size_t)r*D_ + kb + sx*8;
      f32x4 v0 = *(const f32x4*)sp;
      f32x4 v1 = *(const f32x4*)(sp+4);
      short8 pk;
      pk[0]=(short)f2bf(v0[0]); pk[1]=(short)f2bf(v0[1]); pk[2]=(short)f2bf(v0[2]); pk[3]=(short)f2bf(v0[3]);
      pk[4]=(short)f2bf(v1[0]); pk[5]=(short)f2bf(v1[1]); pk[6]=(short)f2bf(v1[2]); pk[7]=(short)f2bf(v1[3]);
      int off = (r*128 + sx*16) ^ ((r&7)<<4);
      *(short8*)((char*)Bs + off) = pk;
    }
    __syncthreads();
    #pragma unroll
    for (int kk=0;kk<2;kk++){
      short8 af[2];
      #pragma unroll
      for (int mi=0;mi<2;mi++){
        int r = 32*w + mi*16 + l15;
        int off = (r*128 + kk*64 + lq*16) ^ ((r&7)<<4);
        af[mi] = *(const short8*)((const char*)As + off);
      }
      #pragma unroll
      for (int nf=0;nf<8;nf++){
        int r = nf*16 + l15;
        int off = (r*128 + kk*64 + lq*16) ^ ((r&7)<<4);
        short8 bfr = *(const short8*)((const char*)Bs + off);
        #pragma unroll
        for (int mi=0;mi<2;mi++)
          acc[mi*8+nf] = __builtin_amdgcn_mfma_f32_16x16x32_bf16(af[mi], bfr, acc[mi*8+nf], 0,0,0);
      }
    }
  }
  #pragma unroll
  for (int mi=0;mi<2;mi++){
    #pragma unroll
    for (int nf=0;nf<8;nf++){
      int col = nf*16 + l15;
      float be = bes[col];
      #pragma unroll
      for (int j=0;j<4;j++){
        int bt = m0 + 32*w + mi*16 + lq*4 + j;
        int b = bt >> 6, tt = bt & 63;
        int gg = b >> 7, rg = (b >> 5) & 3, l31b = b & 31;
        int kw = col >> 4, l5b = (col >> 3) & 1, ee = col & 7;
        size_t byteoff = ((((size_t)tt*32 + gg)*32 + rg*8 + kw) << 10)
                       + (l31b + 32*l5b)*16 + ee*2;
        *(unsigned short*)((char*)encF + byteoff) = f2bf(tanh_(acc[mi*8+nf][j] + be));
      }
    }
  }
}

// ---------------------------------------------------------------------------
// Gate-split LSTM recurrence (R15 + thinner exchange):
// - own-slice ks skipped in staging (overlay already holds it) -> -12.5%
//   exchange volume AND removes the H/D race -> no loop-top barrier.
// - per-slice flags (256 x 128B lines); per-wave lane0 spins on its 2
//   source slices only; loads begin as soon as THOSE producers posted.
// - u64 relaxed agent atomics for the h exchange (2 per 16B).
// 4 barriers/step. 256 blocks x 1024 threads.
// ---------------------------------------------------------------------------
__global__ __launch_bounds__(1024) void rec_kernel(
    const unsigned short* __restrict__ encF,
    const unsigned short* __restrict__ Wf,
    const float* __restrict__ biasc,
    const float* __restrict__ x,
    unsigned short* __restrict__ hgF,     // 2 bufs x [32 g][4 bg][16 ks][1 KB]
    int* __restrict__ cnt,                // 256 x (128B line): [g][s]
    unsigned short* __restrict__ psq,     // [63][8][4096] bf16
    float* __restrict__ out_hn,
    float* __restrict__ out_ldim,
    float* __restrict__ out_ldt){
  extern __shared__ char smem[];
  char* wlds = smem;                      // 96 KB weight A-frags
  char* hbuf = smem + 98304;              // 64 KB [128 rows][256 h] bf16, swizzled
  const int tid = threadIdx.x, lane = tid & 63, w = tid >> 6;
  const int l31 = lane & 31, l5 = lane >> 5;
  const int s  = blockIdx.x >> 5;
  const int g  = blockIdx.x & 31;
  const int b0 = g * 128;
  const int nf = w & 3, bg = w >> 2;

  // weights -> LDS (coalesced, once); zero hbuf (step-0 h = 0)
  {
    const short8* src = (const short8*)(Wf + (size_t)s*49152);
    short8* dst = (short8*)wlds;
    for (int i = tid; i < 6144; i += 1024) dst[i] = src[i];
    short8* hz = (short8*)hbuf;
    for (int i = tid; i < 4096; i += 1024) hz[i] = (short8)(short)0;
  }

  float biasr[16];
  #pragma unroll
  for (int reg=0; reg<16; ++reg){
    int q = reg & 3, hl = nf*8 + 2*(reg>>2) + l5;
    biasr[reg] = biasc[(s*32 + hl)*4 + q];
  }

  const char* abase = wlds + ((nf*24) << 10) + lane*16;                  // + ks<<10
  const char* ebase = (const char*)encF + (((size_t)(g*32 + bg*8)) << 10) + lane*16;

  const int myrow = bg*32 + l31;
  const int swz   = (l31 & 7) << 4;
  const int hrd   = myrow*512 + l5*16;      // + ks*32, ^swz

  // write-pass mapping: wave w -> rows w*8..w*8+8, lane&7 -> h-chunk
  const int row2  = w*8 + (lane >> 3);
  const int swz2  = (row2 & 7) << 4;
  const int hord  = row2*512 + s*64 + (lane & 7)*8;   // ^swz2
  const float* xr = x + (size_t)(b0+row2)*T_*D_ + s*32 + (lane&7)*4;
  float* ltr = out_ldt + (size_t)(b0+row2)*T_*H_ + s*32 + (lane&7)*4;

  // spin sources for this wave: slices {2*(w&3), 2*(w&3)+1} minus own
  const int sA = 2*(w&3), sB = sA + 1;

  float c[4] = {0.f,0.f,0.f,0.f};
  f32x4 ldim = (f32x4)0.f;

  __syncthreads();   // wlds + hbuf ready

  for (int t=0; t<T_; ++t){
    // A. prefetch enc frags + x stripe (flag-independent)
    short8 ef[8];
    #pragma unroll
    for (int kw=0;kw<8;kw++)
      ef[kw] = ntload8((const unsigned short*)(ebase + ((size_t)t<<20) + (kw<<10)));
    f32x4 xv = (f32x4)0.f;
    if (t < T_-1) xv = ntload4f(xr + (size_t)(t+1)*D_);

    // B. enc-part MFMA (cover while flags settle)
    f32x16 a = (f32x16)0.f;
    #pragma unroll
    for (int ks=0; ks<8; ++ks){
      short8 A = *(const short8*)(abase + (ks<<10));
      a = __builtin_amdgcn_mfma_f32_32x32x16_bf16(A, ef[ks], a, 0,0,0);
    }

    // C. per-wave spin on this wave's 2 source slices (lane0 polls)
    if (t > 0 && lane == 0){
      if (sA != s){
        int guard = 0;
        while (__hip_atomic_load(cnt + (g*8+sA)*32, __ATOMIC_RELAXED,
                                 __HIP_MEMORY_SCOPE_AGENT) < t){
          if (++guard > (1<<20)) break;   // bail -> wrong result, not a hang
          __builtin_amdgcn_s_sleep(1);
        }
      }
      if (sB != s){
        int guard = 0;
        while (__hip_atomic_load(cnt + (g*8+sB)*32, __ATOMIC_RELAXED,
                                 __HIP_MEMORY_SCOPE_AGENT) < t){
          if (++guard > (1<<20)) break;
          __builtin_amdgcn_s_sleep(1);
        }
      }
    }

    // D. stage this wave's frags (skip own slice: overlay already has h(t))
    const size_t cbuf = ((size_t)(t&1)) << 21;
    #pragma unroll
    for (int i=0;i<4;i++){
      const int f = w*4 + i;
      const int bgf = f >> 4, ksf = f & 15;
      if ((ksf >> 1) != s){
        const unsigned long long* p = (const unsigned long long*)((const char*)hgF
            + cbuf + (((size_t)((g*4 + bgf)*16 + ksf)) << 10) + lane*16);
        unsigned long long d0 = __hip_atomic_load(p,   __ATOMIC_RELAXED, __HIP_MEMORY_SCOPE_AGENT);
        unsigned long long d1 = __hip_atomic_load(p+1, __ATOMIC_RELAXED, __HIP_MEMORY_SCOPE_AGENT);
        const int row = bgf*32 + l31;
        char* dst = hbuf + ((row*512 + ksf*32 + l5*16) ^ ((row&7)<<4));
        *(unsigned long long*)dst     = d0;
        *(unsigned long long*)(dst+8) = d1;
      }
    }
    __syncthreads();   // bar1: hbuf fully staged

    // E. h-part MFMA (B from LDS)
    #pragma unroll
    for (int ks=0; ks<16; ++ks){
      short8 A  = *(const short8*)(abase + ((8+ks)<<10));
      short8 Bv = *(const short8*)(hbuf + ((hrd + ks*32) ^ swz));
      a = __builtin_amdgcn_mfma_f32_32x32x16_bf16(A, Bv, a, 0,0,0);
    }
    __syncthreads();   // bar2: all hbuf reads done

    // F. pointwise -> h(t+1) overlay into hbuf cols s*32..s*32+32
    #pragma unroll
    for (int r2=0; r2<4; ++r2){
      float gi = sigm_(a[r2*4+0] + biasr[r2*4+0]);
      float gf = sigm_(a[r2*4+1] + biasr[r2*4+1]);
      float gg = tanh_(a[r2*4+2] + biasr[r2*4+2]);
      float go = sigm_(a[r2*4+3] + biasr[r2*4+3]);
      float cn = gf*c[r2] + gi*gg;
      c[r2] = cn;
      float hn = go * tanh_(cn);
      int hl = nf*8 + 2*r2 + l5;
      *(unsigned short*)(hbuf + ((myrow*512 + (s*32+hl)*2) ^ swz)) = f2bf(hn);
    }
    __syncthreads();   // bar3: overlay complete

    // G. repack 8 frags -> hgF[(t+1)&1] (u64 atomic stores), then post flag
    if (t < T_-1){
      if (w < 8){
        int bgr = w >> 1, kwl = w & 1;
        int rrow = bgr*32 + l31;
        short8 hv8 = *(const short8*)(hbuf +
            ((rrow*512 + s*64 + kwl*32 + l5*16) ^ ((rrow&7)<<4)));
        union { short8 sv; unsigned long long u[2]; } cv; cv.sv = hv8;
        unsigned long long* dstp = (unsigned long long*)((char*)hgF
            + (((size_t)((t+1)&1))<<21)
            + (((size_t)((g*4 + bgr)*16 + s*2 + kwl)) << 10) + lane*16);
        __hip_atomic_store(dstp,   cv.u[0], __ATOMIC_RELAXED, __HIP_MEMORY_SCOPE_AGENT);
        __hip_atomic_store(dstp+1, cv.u[1], __ATOMIC_RELAXED, __HIP_MEMORY_SCOPE_AGENT);
      }
      __syncthreads();  // bar4: stores drained (vmcnt0 before s_barrier)
      if (tid == 0)
        __hip_atomic_fetch_add(cnt + (g*8+s)*32, 1, __ATOMIC_RELAXED,
                               __HIP_MEMORY_SCOPE_AGENT);
    }

    // H. write-pass (after post; reads ONLY overlay cols -> disjoint from
    // next step's D, which skips own-slice ks)
    u32x2 hb = *(const u32x2*)(hbuf + (hord ^ swz2));
    f32x4 hf;
    hf[0] = bf2f((unsigned short)(hb[0] & 0xFFFFu));
    hf[1] = bf2f((unsigned short)(hb[0] >> 16));
    hf[2] = bf2f((unsigned short)(hb[1] & 0xFFFFu));
    hf[3] = bf2f((unsigned short)(hb[1] >> 16));
    float* ltp = ltr + (size_t)t*H_;
    if (t < T_-1){
      f32x4 d;
      d[0] = fabsf(hf[0] - xv[0]);
      d[1] = fabsf(hf[1] - xv[1]);
      d[2] = fabsf(hf[2] - xv[2]);
      d[3] = fabsf(hf[3] - xv[3]);
      __builtin_nontemporal_store(d, (f32x4*)ltp);
      ldim += d;
      float ss = d[0]*d[0] + d[1]*d[1] + d[2]*d[2] + d[3]*d[3];
      ss += __shfl_xor(ss, 1);
      ss += __shfl_xor(ss, 2);
      ss += __shfl_xor(ss, 4);
      if ((lane & 7) == 0)
        psq[((size_t)t*8 + s)*4096 + b0 + row2] = f2bf(ss);
    } else {
      __builtin_nontemporal_store((f32x4)0.f, (f32x4*)ltp);
      __builtin_nontemporal_store(hf,
          (f32x4*)(out_hn + (size_t)(b0+row2)*H_ + s*32 + (lane&7)*4));
    }
  }

  // epilogue: loss_dim
  *(f32x4*)(out_ldim + (size_t)(b0+row2)*H_ + s*32 + (lane&7)*4) = ldim * (1.f/63.f);
}

// ---------------------------------------------------------------------------
// final: loss[b] = (1/63) sum_t sqrt(sum_s psq[t][s][b]). grid 16 x 256.
// ---------------------------------------------------------------------------
__global__ __launch_bounds__(256) void final_kernel(
    const unsigned short* __restrict__ psq, float* __restrict__ out_loss){
  const int w = threadIdx.x >> 6, lane = threadIdx.x & 63;
  const int b = (blockIdx.x*4 + w)*64 + lane;
  float lacc = 0.f;
  for (int t=0;t<T_-1;++t){
    float sum = 0.f;
    #pragma unroll
    for (int s=0;s<8;s++) sum += bf2f(psq[((size_t)t*8 + s)*4096 + b]);
    lacc += sqrtf(sum);
  }
  out_loss[b] = lacc * (1.f/63.f);
}

// ---------------------------------------------------------------------------
extern "C" void kernel_launch(void* const* d_in, const int* in_sizes, int n_in,
                              void* d_out, int out_size, void* d_ws, size_t ws_size,
                              hipStream_t stream){
  const float* x     = (const float*)d_in[0];
  const float* W_enc = (const float*)d_in[1];
  const float* b_enc = (const float*)d_in[2];
  const float* W_ih  = (const float*)d_in[3];
  const float* b_ih  = (const float*)d_in[4];
  const float* W_hh  = (const float*)d_in[5];
  const float* b_hh  = (const float*)d_in[6];

  // ws: encF 64MB | Wf 768KB | biasc 4KB | hgF 4MB | cnt 32KB | psq 4MB
  char* ws = (char*)d_ws;
  unsigned short* encF  = (unsigned short*)(ws);                 // 67,108,864
  unsigned short* Wf    = (unsigned short*)(ws + 67108864);      //    786,432
  float*          biasc = (float*)         (ws + 67895296);      //      4,096
  unsigned short* hgF   = (unsigned short*)(ws + 67899392);      //  4,194,304
  int*            cnt   = (int*)           (ws + 72093696);      //     32,768
  unsigned short* psq   = (unsigned short*)(ws + 72126464);      //  4,128,768

  float* out_hn   = (float*)d_out;
  float* out_loss = out_hn  + (size_t)B_*H_;
  float* out_ldim = out_loss + B_;
  float* out_ldt  = out_ldim + (size_t)B_*H_;

  (void)hipFuncSetAttribute((const void*)rec_kernel,
      hipFuncAttributeMaxDynamicSharedMemorySize, 163840);

  init_kernel<<<1536, 256, 0, stream>>>(W_ih, b_ih, W_hh, b_hh, Wf, biasc, hgF, cnt);
  enc_kernel<<<2048, 256, 0, stream>>>(x, W_enc, b_enc, encF);
  rec_kernel<<<256, 1024, 163840, stream>>>(encF, Wf, biasc, x, hgF, cnt, psq,
                                            out_hn, out_ldim, out_ldt);
  final_kernel<<<16, 256, 0, stream>>>(psq, out_loss);
}

// Round 17
// 684.968 us; speedup vs baseline: 5.1334x; 1.2020x over previous
//
#include <hip/hip_runtime.h>

// Problem constants
#define B_  4096
#define T_  64
#define D_  256
#define E_  128
#define H_  256

typedef __attribute__((ext_vector_type(8))) short short8;
typedef __attribute__((ext_vector_type(4))) float f32x4;
typedef __attribute__((ext_vector_type(16))) float f32x16;
typedef __attribute__((ext_vector_type(2))) unsigned int u32x2;

__device__ inline unsigned short f2bf(float f){
  unsigned u = __float_as_uint(f);
  u += 0x7FFFu + ((u >> 16) & 1u);   // RNE
  return (unsigned short)(u >> 16);
}
__device__ inline float bf2f(unsigned short v){
  return __uint_as_float(((unsigned)v) << 16);
}
__device__ inline float sigm_(float x){ return __fdividef(1.f, 1.f + __expf(-x)); }
__device__ inline float tanh_(float x){
  float e = __expf(2.f * fminf(fmaxf(x, -15.f), 15.f));
  return __fdividef(e - 1.f, e + 1.f);
}
__device__ inline short8 ntload8(const unsigned short* p){
  return __builtin_nontemporal_load((const short8*)p);
}
__device__ inline f32x4 ntload4f(const float* p){
  return __builtin_nontemporal_load((const f32x4*)p);
}

// ---------------------------------------------------------------------------
// init: pack weights as 32x32x16 MFMA A-fragments per slice (R12/R13 layout).
// biasc[h*4+q]; zero hgF buf0 (2 MB); zero cnt (256 x 128B lines).
// ---------------------------------------------------------------------------
__global__ __launch_bounds__(256) void init_kernel(
    const float* __restrict__ W_ih, const float* __restrict__ b_ih,
    const float* __restrict__ W_hh, const float* __restrict__ b_hh,
    unsigned short* __restrict__ Wf, float* __restrict__ biasc,
    unsigned short* __restrict__ hgF, int* __restrict__ cnt){
  const int idx  = blockIdx.x*256 + threadIdx.x;
  const int e    = idx & 7;
  const int l    = (idx >> 3) & 63;
  const int fk   = idx >> 9;          // (s*4+nf)*24 + ks
  const int ks   = fk % 24;
  const int nfs  = fk / 24;
  const int nf   = nfs & 3;
  const int s    = nfs >> 2;
  const int r    = l & 31;
  const int q    = r & 3;
  const int hl   = r >> 2;
  const int h    = s*32 + nf*8 + hl;
  const int k    = ks*16 + (l >> 5)*8 + e;
  const int g    = q*H_ + h;
  float v = (k < E_) ? W_ih[g*E_ + k] : W_hh[g*H_ + (k - E_)];
  Wf[idx] = f2bf(v);
  if (idx < 4*H_){
    int hh = idx >> 2, qq = idx & 3, gg = qq*H_ + hh;
    biasc[idx] = b_ih[gg] + b_hh[gg];
  }
  if (idx < 262144) ((unsigned long long*)hgF)[idx] = 0ull;   // buf0 = 2 MB zeros
  if (idx < 8192) cnt[idx] = 0;
}

// ---------------------------------------------------------------------------
// enc: encF = bf16(tanh(x @ W_enc^T + b_enc)) in B-fragment order (R12).
// ---------------------------------------------------------------------------
__global__ __launch_bounds__(256) void enc_kernel(
    const float* __restrict__ x, const float* __restrict__ W_enc,
    const float* __restrict__ b_enc, unsigned short* __restrict__ encF){
  __shared__ unsigned short As[128*64];
  __shared__ unsigned short Bs[128*64];
  __shared__ float bes[128];
  const int tid = threadIdx.x;
  const int lane = tid & 63, w = tid >> 6;
  const int l15 = lane & 15, lq = lane >> 4;
  const int m0 = blockIdx.x * 128;
  if (tid < 128) bes[tid] = b_enc[tid];

  f32x4 acc[16];
  #pragma unroll
  for (int i=0;i<16;i++) acc[i] = (f32x4)0.f;

  for (int kc = 0; kc < 4; ++kc){
    const int kb = kc*64;
    __syncthreads();
    #pragma unroll
    for (int i=0;i<4;i++){
      int u = i*256 + tid; int r = u>>3, sx = u&7;
      const float* sp = x + (size_t)(m0+r)*D_ + kb + sx*8;
      f32x4 v0 = ntload4f(sp);
      f32x4 v1 = ntload4f(sp+4);
      short8 pk;
      pk[0]=(short)f2bf(v0[0]); pk[1]=(short)f2bf(v0[1]); pk[2]=(short)f2bf(v0[2]); pk[3]=(short)f2bf(v0[3]);
      pk[4]=(short)f2bf(v1[0]); pk[5]=(short)f2bf(v1[1]); pk[6]=(short)f2bf(v1[2]); pk[7]=(short)f2bf(v1[3]);
      int off = (r*128 + sx*16) ^ ((r&7)<<4);
      *(short8*)((char*)As + off) = pk;
    }
    #pragma unroll
    for (int i=0;i<4;i++){
      int u = i*256 + tid; int r = u>>3, sx = u&7;
      const float* sp = W_enc + (size_t)r*D_ + kb + sx*8;
      f32x4 v0 = *(const f32x4*)sp;
      f32x4 v1 = *(const f32x4*)(sp+4);
      short8 pk;
      pk[0]=(short)f2bf(v0[0]); pk[1]=(short)f2bf(v0[1]); pk[2]=(short)f2bf(v0[2]); pk[3]=(short)f2bf(v0[3]);
      pk[4]=(short)f2bf(v1[0]); pk[5]=(short)f2bf(v1[1]); pk[6]=(short)f2bf(v1[2]); pk[7]=(short)f2bf(v1[3]);
      int off = (r*128 + sx*16) ^ ((r&7)<<4);
      *(short8*)((char*)Bs + off) = pk;
    }
    __syncthreads();
    #pragma unroll
    for (int kk=0;kk<2;kk++){
      short8 af[2];
      #pragma unroll
      for (int mi=0;mi<2;mi++){
        int r = 32*w + mi*16 + l15;
        int off = (r*128 + kk*64 + lq*16) ^ ((r&7)<<4);
        af[mi] = *(const short8*)((const char*)As + off);
      }
      #pragma unroll
      for (int nf=0;nf<8;nf++){
        int r = nf*16 + l15;
        int off = (r*128 + kk*64 + lq*16) ^ ((r&7)<<4);
        short8 bfr = *(const short8*)((const char*)Bs + off);
        #pragma unroll
        for (int mi=0;mi<2;mi++)
          acc[mi*8+nf] = __builtin_amdgcn_mfma_f32_16x16x32_bf16(af[mi], bfr, acc[mi*8+nf], 0,0,0);
      }
    }
  }
  #pragma unroll
  for (int mi=0;mi<2;mi++){
    #pragma unroll
    for (int nf=0;nf<8;nf++){
      int col = nf*16 + l15;
      float be = bes[col];
      #pragma unroll
      for (int j=0;j<4;j++){
        int bt = m0 + 32*w + mi*16 + lq*4 + j;
        int b = bt >> 6, tt = bt & 63;
        int gg = b >> 7, rg = (b >> 5) & 3, l31b = b & 31;
        int kw = col >> 4, l5b = (col >> 3) & 1, ee = col & 7;
        size_t byteoff = ((((size_t)tt*32 + gg)*32 + rg*8 + kw) << 10)
                       + (l31b + 32*l5b)*16 + ee*2;
        *(unsigned short*)((char*)encF + byteoff) = f2bf(tanh_(acc[mi*8+nf][j] + be));
      }
    }
  }
}

// ---------------------------------------------------------------------------
// Gate-split LSTM recurrence (R16 + frag-order hbuf + dwordx4 sc0sc1 loads):
// - hbuf is FRAGMENT-ordered [4 bg][16 ks] x 1KB (same as hgF): D-stores,
//   E B-frag reads, G repack reads are contiguous 1KB/wave -> no conflicts.
// - D loads: global_load_dwordx4 sc0 sc1 (coherent 16B messages, half the
//   message count of u64 atomics); one vmcnt(0)+sched_barrier before stores.
// - own-slice frags never staged (own overlay IS h(t) own-slice); H reads
//   own-slice only -> disjoint from next D.
// 4 barriers/step. 256 blocks x 1024 threads.
// ---------------------------------------------------------------------------
__global__ __launch_bounds__(1024) void rec_kernel(
    const unsigned short* __restrict__ encF,
    const unsigned short* __restrict__ Wf,
    const float* __restrict__ biasc,
    const float* __restrict__ x,
    unsigned short* __restrict__ hgF,     // 2 bufs x [32 g][64 frag][1 KB]
    int* __restrict__ cnt,                // 256 x (128B line): [g][s]
    unsigned short* __restrict__ psq,     // [63][8][4096] bf16
    float* __restrict__ out_hn,
    float* __restrict__ out_ldim,
    float* __restrict__ out_ldt){
  extern __shared__ char smem[];
  char* wlds = smem;                      // 96 KB weight A-frags
  char* hbuf = smem + 98304;              // 64 KB frag-order [bg*16+ks][1KB]
  const int tid = threadIdx.x, lane = tid & 63, w = tid >> 6;
  const int l31 = lane & 31, l5 = lane >> 5;
  const int s  = blockIdx.x >> 5;
  const int g  = blockIdx.x & 31;
  const int b0 = g * 128;
  const int nf = w & 3, bg = w >> 2;

  // weights -> LDS (coalesced, once); zero hbuf (step-0 h = 0)
  {
    const short8* src = (const short8*)(Wf + (size_t)s*49152);
    short8* dst = (short8*)wlds;
    for (int i = tid; i < 6144; i += 1024) dst[i] = src[i];
    short8* hz = (short8*)hbuf;
    for (int i = tid; i < 4096; i += 1024) hz[i] = (short8)(short)0;
  }

  float biasr[16];
  #pragma unroll
  for (int reg=0; reg<16; ++reg){
    int q = reg & 3, hl = nf*8 + 2*(reg>>2) + l5;
    biasr[reg] = biasc[(s*32 + hl)*4 + q];
  }

  const char* abase = wlds + ((nf*24) << 10) + lane*16;                  // + ks<<10
  const char* ebase = (const char*)encF + (((size_t)(g*32 + bg*8)) << 10) + lane*16;
  const char* hfb   = hbuf + ((bg*16) << 10) + lane*16;                  // + ks<<10

  // write-pass mapping: wave w -> rows w*8..w*8+8, lane&7 -> 4-col chunk
  const int row2 = w*8 + (lane >> 3);
  const int bg2  = row2 >> 5;
  const int cloc = (lane & 7)*4;          // col within slice [0,32)
  const int hfo  = ((bg2*16 + s*2 + (cloc>>4)) << 10)
                 + ((row2 & 31) + ((cloc & 15) >> 3)*32)*16 + (cloc & 7)*2;
  const float* xr = x + (size_t)(b0+row2)*T_*D_ + s*32 + cloc;
  float* ltr = out_ldt + (size_t)(b0+row2)*T_*H_ + s*32 + cloc;

  // spin sources for this wave: slices {2*(w&3), 2*(w&3)+1} minus own
  const int sA = 2*(w&3), sB = sA + 1;

  float c[4] = {0.f,0.f,0.f,0.f};
  f32x4 ldim = (f32x4)0.f;

  __syncthreads();   // wlds + hbuf ready

  for (int t=0; t<T_; ++t){
    // A. prefetch enc frags + x stripe (flag-independent)
    short8 ef[8];
    #pragma unroll
    for (int kw=0;kw<8;kw++)
      ef[kw] = ntload8((const unsigned short*)(ebase + ((size_t)t<<20) + (kw<<10)));
    f32x4 xv = (f32x4)0.f;
    if (t < T_-1) xv = ntload4f(xr + (size_t)(t+1)*D_);

    // B. enc-part MFMA (cover while flags settle)
    f32x16 a = (f32x16)0.f;
    #pragma unroll
    for (int ks=0; ks<8; ++ks){
      short8 A = *(const short8*)(abase + (ks<<10));
      a = __builtin_amdgcn_mfma_f32_32x32x16_bf16(A, ef[ks], a, 0,0,0);
    }

    // C. per-wave spin on this wave's 2 source slices (lane0 polls)
    if (t > 0 && lane == 0){
      if (sA != s){
        int guard = 0;
        while (__hip_atomic_load(cnt + (g*8+sA)*32, __ATOMIC_RELAXED,
                                 __HIP_MEMORY_SCOPE_AGENT) < t){
          if (++guard > (1<<20)) break;   // bail -> wrong result, not a hang
          __builtin_amdgcn_s_sleep(1);
        }
      }
      if (sB != s){
        int guard = 0;
        while (__hip_atomic_load(cnt + (g*8+sB)*32, __ATOMIC_RELAXED,
                                 __HIP_MEMORY_SCOPE_AGENT) < t){
          if (++guard > (1<<20)) break;
          __builtin_amdgcn_s_sleep(1);
        }
      }
    }

    // D. stage this wave's frags (skip own slice). 16B coherent loads.
    const size_t cbuf = ((size_t)(t&1)) << 21;
    short8 dv0, dv1, dv2, dv3;
    {
      const char* pb = (const char*)hgF + cbuf + (((size_t)(g*64 + w*4)) << 10) + lane*16;
      if (((w*4+0) & 15) >> 1 != s)
        asm volatile("global_load_dwordx4 %0, %1, off sc0 sc1" : "=&v"(dv0) : "v"(pb)        : "memory");
      if (((w*4+1) & 15) >> 1 != s)
        asm volatile("global_load_dwordx4 %0, %1, off sc0 sc1" : "=&v"(dv1) : "v"(pb+1024)   : "memory");
      if (((w*4+2) & 15) >> 1 != s)
        asm volatile("global_load_dwordx4 %0, %1, off sc0 sc1" : "=&v"(dv2) : "v"(pb+2048)   : "memory");
      if (((w*4+3) & 15) >> 1 != s)
        asm volatile("global_load_dwordx4 %0, %1, off sc0 sc1" : "=&v"(dv3) : "v"(pb+3072)   : "memory");
    }
    asm volatile("s_waitcnt vmcnt(0)" ::: "memory");
    __builtin_amdgcn_sched_barrier(0);
    {
      char* db = hbuf + ((w*4) << 10) + lane*16;
      if (((w*4+0) & 15) >> 1 != s) *(short8*)(db)        = dv0;
      if (((w*4+1) & 15) >> 1 != s) *(short8*)(db + 1024) = dv1;
      if (((w*4+2) & 15) >> 1 != s) *(short8*)(db + 2048) = dv2;
      if (((w*4+3) & 15) >> 1 != s) *(short8*)(db + 3072) = dv3;
    }
    __syncthreads();   // bar1: hbuf fully staged

    // E. h-part MFMA (B-frags contiguous from LDS, conflict-free)
    #pragma unroll
    for (int ks=0; ks<16; ++ks){
      short8 A  = *(const short8*)(abase + ((8+ks)<<10));
      short8 Bv = *(const short8*)(hfb + (ks<<10));
      a = __builtin_amdgcn_mfma_f32_32x32x16_bf16(A, Bv, a, 0,0,0);
    }
    __syncthreads();   // bar2: all hbuf reads done

    // F. pointwise -> h(t+1) overlay into own-slice frags
    #pragma unroll
    for (int r2=0; r2<4; ++r2){
      float gi = sigm_(a[r2*4+0] + biasr[r2*4+0]);
      float gf = sigm_(a[r2*4+1] + biasr[r2*4+1]);
      float gg = tanh_(a[r2*4+2] + biasr[r2*4+2]);
      float go = sigm_(a[r2*4+3] + biasr[r2*4+3]);
      float cn = gf*c[r2] + gi*gg;
      c[r2] = cn;
      float hn = go * tanh_(cn);
      int hl = nf*8 + 2*r2 + l5;          // col within slice [0,32)
      int fr = bg*16 + s*2 + (hl>>4);
      int cl = hl & 15;
      *(unsigned short*)(hbuf + (fr<<10) + (l31 + ((cl>>3)<<5))*16 + (cl&7)*2) = f2bf(hn);
    }
    __syncthreads();   // bar3: overlay complete

    // G. repack own-slice frags -> hgF[(t+1)&1], then post flag
    if (t < T_-1){
      if (w < 8){
        int bgr = w >> 1, kwl = w & 1;
        int fr = bgr*16 + s*2 + kwl;
        short8 hv8 = *(const short8*)(hbuf + (fr<<10) + lane*16);
        union { short8 sv; unsigned long long u[2]; } cv; cv.sv = hv8;
        unsigned long long* dstp = (unsigned long long*)((char*)hgF
            + (((size_t)((t+1)&1))<<21)
            + (((size_t)(g*64 + fr)) << 10) + lane*16);
        __hip_atomic_store(dstp,   cv.u[0], __ATOMIC_RELAXED, __HIP_MEMORY_SCOPE_AGENT);
        __hip_atomic_store(dstp+1, cv.u[1], __ATOMIC_RELAXED, __HIP_MEMORY_SCOPE_AGENT);
      }
      __syncthreads();  // bar4: stores drained (vmcnt0 before s_barrier)
      if (tid == 0)
        __hip_atomic_fetch_add(cnt + (g*8+s)*32, 1, __ATOMIC_RELAXED,
                               __HIP_MEMORY_SCOPE_AGENT);
    }

    // H. write-pass (after post; reads ONLY own-slice frags -> disjoint
    // from next step's D, which skips own-slice)
    u32x2 hb = *(const u32x2*)(hbuf + hfo);
    f32x4 hf;
    hf[0] = bf2f((unsigned short)(hb[0] & 0xFFFFu));
    hf[1] = bf2f((unsigned short)(hb[0] >> 16));
    hf[2] = bf2f((unsigned short)(hb[1] & 0xFFFFu));
    hf[3] = bf2f((unsigned short)(hb[1] >> 16));
    float* ltp = ltr + (size_t)t*H_;
    if (t < T_-1){
      f32x4 d;
      d[0] = fabsf(hf[0] - xv[0]);
      d[1] = fabsf(hf[1] - xv[1]);
      d[2] = fabsf(hf[2] - xv[2]);
      d[3] = fabsf(hf[3] - xv[3]);
      __builtin_nontemporal_store(d, (f32x4*)ltp);
      ldim += d;
      float ss = d[0]*d[0] + d[1]*d[1] + d[2]*d[2] + d[3]*d[3];
      ss += __shfl_xor(ss, 1);
      ss += __shfl_xor(ss, 2);
      ss += __shfl_xor(ss, 4);
      if ((lane & 7) == 0)
        psq[((size_t)t*8 + s)*4096 + b0 + row2] = f2bf(ss);
    } else {
      __builtin_nontemporal_store((f32x4)0.f, (f32x4*)ltp);
      __builtin_nontemporal_store(hf,
          (f32x4*)(out_hn + (size_t)(b0+row2)*H_ + s*32 + cloc));
    }
  }

  // epilogue: loss_dim
  *(f32x4*)(out_ldim + (size_t)(b0+row2)*H_ + s*32 + cloc) = ldim * (1.f/63.f);
}

// ---------------------------------------------------------------------------
// final: loss[b] = (1/63) sum_t sqrt(sum_s psq[t][s][b]).
// grid 64 x 256: 4 waves split t-range, LDS combine.
// ---------------------------------------------------------------------------
__global__ __launch_bounds__(256) void final_kernel(
    const unsigned short* __restrict__ psq, float* __restrict__ out_loss){
  __shared__ float part[4][64];
  const int w = threadIdx.x >> 6, lane = threadIdx.x & 63;
  const int b = blockIdx.x*64 + lane;
  const int t0 = w*16;
  const int nt = (w==3) ? 15 : 16;
  float lacc = 0.f;
  for (int ti=0; ti<nt; ++ti){
    int t = t0 + ti;
    float sum = 0.f;
    #pragma unroll
    for (int s=0;s<8;s++) sum += bf2f(psq[((size_t)t*8 + s)*4096 + b]);
    lacc += sqrtf(sum);
  }
  part[w][lane] = lacc;
  __syncthreads();
  if (w == 0)
    out_loss[b] = (part[0][lane]+part[1][lane]+part[2][lane]+part[3][lane])
                  * (1.f/63.f);
}

// ---------------------------------------------------------------------------
extern "C" void kernel_launch(void* const* d_in, const int* in_sizes, int n_in,
                              void* d_out, int out_size, void* d_ws, size_t ws_size,
                              hipStream_t stream){
  const float* x     = (const float*)d_in[0];
  const float* W_enc = (const float*)d_in[1];
  const float* b_enc = (const float*)d_in[2];
  const float* W_ih  = (const float*)d_in[3];
  const float* b_ih  = (const float*)d_in[4];
  const float* W_hh  = (const float*)d_in[5];
  const float* b_hh  = (const float*)d_in[6];

  // ws: encF 64MB | Wf 768KB | biasc 4KB | hgF 4MB | cnt 32KB | psq 4MB
  char* ws = (char*)d_ws;
  unsigned short* encF  = (unsigned short*)(ws);                 // 67,108,864
  unsigned short* Wf    = (unsigned short*)(ws + 67108864);      //    786,432
  float*          biasc = (float*)         (ws + 67895296);      //      4,096
  unsigned short* hgF   = (unsigned short*)(ws + 67899392);      //  4,194,304
  int*            cnt   = (int*)           (ws + 72093696);      //     32,768
  unsigned short* psq   = (unsigned short*)(ws + 72126464);      //  4,128,768

  float* out_hn   = (float*)d_out;
  float* out_loss = out_hn  + (size_t)B_*H_;
  float* out_ldim = out_loss + B_;
  float* out_ldt  = out_ldim + (size_t)B_*H_;

  (void)hipFuncSetAttribute((const void*)rec_kernel,
      hipFuncAttributeMaxDynamicSharedMemorySize, 163840);

  init_kernel<<<1536, 256, 0, stream>>>(W_ih, b_ih, W_hh, b_hh, Wf, biasc, hgF, cnt);
  enc_kernel<<<2048, 256, 0, stream>>>(x, W_enc, b_enc, encF);
  rec_kernel<<<256, 1024, 163840, stream>>>(encF, Wf, biasc, x, hgF, cnt, psq,
                                            out_hn, out_ldim, out_ldt);
  final_kernel<<<64, 256, 0, stream>>>(psq, out_loss);
}